// Round 1
// baseline (2636.663 us; speedup 1.0000x reference)
//
#include <hip/hip_runtime.h>

#define B_ 128
#define K_ 25
#define DEG_ 16

// ---------------- transpose x: (B=128, N=4096) -> x0 (4096, 128)
__global__ void k_transpose_x(const float* __restrict__ x, float* __restrict__ x0) {
    int i = blockIdx.x * 256 + threadIdx.x;   // i = v*128 + b
    int v = i >> 7, b = i & 127;
    x0[i] = x[(b << 12) + v];
}

// ---------------- SpMM step: next = two ? 2*L*cur - prev : L*cur
// L is fixed-degree (16/row): row v entries at [v*16, v*16+16)
// SWIZ: XCD-aware column-slab mapping (blockIdx & 7 -> slab) for L2 residency
template<int LOGC, int SWIZ>
__global__ void k_spmm(const int* __restrict__ cols, const float* __restrict__ vals,
                       const float* __restrict__ cur, const float* __restrict__ prev,
                       float* __restrict__ next, int two) {
    int v, c;
    if constexpr (SWIZ) {
        constexpr int LOGSLAB = LOGC - 3;            // C/8 columns per XCD slab
        constexpr int BPV = (1 << LOGSLAB) >> 8;     // 256-thread blocks per (v, slab)
        int blk = blockIdx.x;
        int xcd = blk & 7, q = blk >> 3;
        v = q / BPV;
        c = (xcd << LOGSLAB) + ((q & (BPV - 1)) << 8) + threadIdx.x;
    } else {
        int i = blockIdx.x * 256 + threadIdx.x;
        v = i >> LOGC;
        c = i & ((1 << LOGC) - 1);
    }
    int base = v * DEG_;
    float s = 0.f;
#pragma unroll
    for (int d = 0; d < DEG_; ++d) {
        s += vals[base + d] * cur[((size_t)cols[base + d] << LOGC) + c];
    }
    size_t idx = ((size_t)v << LOGC) + c;
    next[idx] = two ? 2.f * s - prev[idx] : s;
}

// ---------------- layer 1 projection (Fin=1, Fout=32) + bias + relu + pool4, full basis (25 slots)
__global__ void k_proj1_pool(const float* __restrict__ basis, const float* __restrict__ W1,
                             const float* __restrict__ b1, float* __restrict__ pool1) {
    __shared__ float w[K_ * 32];
    for (int j = threadIdx.x; j < K_ * 32; j += 256) w[j] = W1[j];
    __syncthreads();
    int i = blockIdx.x * 256 + threadIdx.x;   // i = g*128 + b, g in [0,1024)
    int g = i >> 7, b = i & 127;
    float m[32];
#pragma unroll
    for (int fo = 0; fo < 32; ++fo) m[fo] = -1e30f;
    for (int r = 0; r < 4; ++r) {
        int v = 4 * g + r;
        float acc[32];
#pragma unroll
        for (int fo = 0; fo < 32; ++fo) acc[fo] = 0.f;
        for (int k = 0; k < K_; ++k) {
            float tv = basis[(size_t)k * (4096 * 128) + (v << 7) + b];
#pragma unroll
            for (int fo = 0; fo < 32; ++fo) acc[fo] += tv * w[k * 32 + fo];
        }
#pragma unroll
        for (int fo = 0; fo < 32; ++fo) m[fo] = fmaxf(m[fo], acc[fo]);
    }
#pragma unroll
    for (int fo = 0; fo < 32; ++fo)
        pool1[(g << 12) + (fo << 7) + b] = fmaxf(m[fo] + b1[fo], 0.f);
}

// ---------------- init accumulator with bias: acc[(v*F+fo)*128 + b] = bias[fo]
template<int LOGF>
__global__ void k_init_acc(float* __restrict__ acc, const float* __restrict__ bias, int total) {
    int i = blockIdx.x * 256 + threadIdx.x;
    if (i < total) acc[i] = bias[(i >> 7) & ((1 << LOGF) - 1)];
}

// ---------------- chunk projection: acc[v][fo][b] += sum_{kk,fi} basis[kk][v][fi][b] * W[fi*25+k0+kk][fo]
// grid.y splits Fout into FOUT/FOS slices. k0 % CK == 0 so slot(k0+kk) == kk.
template<int FIN, int FOUT, int FOS, int MAXK>
__global__ void k_proj_chunk(const float* __restrict__ basis, long slotStride,
                             const float* __restrict__ W, float* __restrict__ acc,
                             int k0, int kcnt) {
    __shared__ float w[MAXK * FIN * FOS];
    int fo0 = blockIdx.y * FOS;
    for (int j = threadIdx.x; j < kcnt * FIN * FOS; j += 256) {
        int kk = j / (FIN * FOS);
        int rem = j - kk * (FIN * FOS);
        int fi = rem / FOS, fo = rem - fi * FOS;
        w[j] = W[((size_t)fi * K_ + (k0 + kk)) * FOUT + fo0 + fo];
    }
    __syncthreads();
    int i = blockIdx.x * 256 + threadIdx.x;   // i = v*128 + b
    int v = i >> 7, b = i & 127;
    float a[FOS];
    float* ap = acc + ((size_t)v * FOUT + fo0) * B_ + b;
#pragma unroll
    for (int fo = 0; fo < FOS; ++fo) a[fo] = ap[fo * B_];
    for (int kk = 0; kk < kcnt; ++kk) {
        const float* bp = basis + (size_t)kk * slotStride + (size_t)(v * FIN) * B_ + b;
        const float* wp = w + kk * (FIN * FOS);
        for (int fi = 0; fi < FIN; ++fi) {
            float tv = bp[(size_t)fi * B_];
#pragma unroll
            for (int fo = 0; fo < FOS; ++fo) a[fo] += tv * wp[fi * FOS + fo];
        }
    }
#pragma unroll
    for (int fo = 0; fo < FOS; ++fo) ap[fo * B_] = a[fo];
}

// ---------------- relu + pool4 over nodes: pool[g][rem] = max(0, max_r acc[4g+r][rem])
template<int LOGFB>
__global__ void k_relu_pool(const float* __restrict__ acc, float* __restrict__ pool) {
    int i = blockIdx.x * 256 + threadIdx.x;
    int g = i >> LOGFB, rem = i & ((1 << LOGFB) - 1);
    float m = 0.f;
#pragma unroll
    for (int r = 0; r < 4; ++r) m = fmaxf(m, acc[((size_t)(4 * g + r) << LOGFB) + rem]);
    pool[i] = m;
}

// ---------------- FC1 partials: rowsplit 8, 8 b's per thread
__global__ void k_fc1_part(const float* __restrict__ t3, const float* __restrict__ w,
                           float* __restrict__ part) {
    int T = blockIdx.x * 256 + threadIdx.x;   // 65536 threads
    int j = T & 511;
    int bg = (T >> 9) & 15;
    int rs = T >> 13;                          // 0..7
    int b0 = bg << 3;
    float a[8];
#pragma unroll
    for (int q = 0; q < 8; ++q) a[q] = 0.f;
    int r0 = rs << 11;
    for (int row = r0; row < r0 + 2048; ++row) {
        float wv = w[(size_t)row * 512 + j];
        const float* tp = t3 + (size_t)row * B_ + b0;
#pragma unroll
        for (int q = 0; q < 8; ++q) a[q] += fmaxf(tp[q], 0.f) * wv;
    }
#pragma unroll
    for (int q = 0; q < 8; ++q) part[((size_t)rs * B_ + b0 + q) * 512 + j] = a[q];
}

__global__ void k_fc1_red(const float* __restrict__ part, const float* __restrict__ bias,
                          float* __restrict__ h) {
    int i = blockIdx.x * 256 + threadIdx.x;   // i = b*512 + j
    float a = bias[i & 511];
#pragma unroll
    for (int rs = 0; rs < 8; ++rs) a += part[((size_t)rs << 16) + i];
    h[i] = a;
}

// ---------------- batchnorm stats over batch (biased var), store mean | inv_std
__global__ void k_bnstats(const float* __restrict__ h, float* __restrict__ mv) {
    __shared__ float s1[128], s2[128];
    int j = blockIdx.x, t = threadIdx.x;
    float v = h[(size_t)t * 512 + j];
    s1[t] = v; s2[t] = v * v;
    __syncthreads();
    for (int o = 64; o > 0; o >>= 1) {
        if (t < o) { s1[t] += s1[t + o]; s2[t] += s2[t + o]; }
        __syncthreads();
    }
    if (t == 0) {
        float m = s1[0] * (1.f / 128.f);
        float var = s2[0] * (1.f / 128.f) - m * m;
        mv[j] = m;
        mv[512 + j] = rsqrtf(var + 1e-5f);
    }
}

// ---------------- BN apply + relu + FC2 + log_softmax, one block per batch row
__global__ void k_head(const float* __restrict__ h, const float* __restrict__ mv,
                       const float* __restrict__ gamma, const float* __restrict__ beta,
                       const float* __restrict__ w2, const float* __restrict__ b2,
                       float* __restrict__ out) {
    __shared__ float hr[512];
    __shared__ float lg[16];
    int b = blockIdx.x, t = threadIdx.x;   // 64 threads
    for (int j = t; j < 512; j += 64) {
        float x = (h[(size_t)b * 512 + j] - mv[j]) * mv[512 + j] * gamma[j] + beta[j];
        hr[j] = fmaxf(x, 0.f);
    }
    __syncthreads();
    if (t < 10) {
        float a = b2[t];
        for (int j = 0; j < 512; ++j) a += hr[j] * w2[j * 10 + t];
        lg[t] = a;
    }
    __syncthreads();
    if (t == 0) {
        float mx = -1e30f;
        for (int q = 0; q < 10; ++q) mx = fmaxf(mx, lg[q]);
        float sum = 0.f;
        for (int q = 0; q < 10; ++q) sum += expf(lg[q] - mx);
        float ls = logf(sum) + mx;
        for (int q = 0; q < 10; ++q) out[b * 10 + q] = lg[q] - ls;
    }
}

extern "C" void kernel_launch(void* const* d_in, const int* in_sizes, int n_in,
                              void* d_out, int out_size, void* d_ws, size_t ws_size,
                              hipStream_t stream) {
    (void)in_sizes; (void)n_in; (void)out_size;
    const float* x      = (const float*)d_in[0];
    const int*   l0cols = (const int*)d_in[2];
    const float* l0vals = (const float*)d_in[3];
    const int*   l2cols = (const int*)d_in[5];
    const float* l2vals = (const float*)d_in[6];
    const int*   l4cols = (const int*)d_in[8];
    const float* l4vals = (const float*)d_in[9];
    const float* w1   = (const float*)d_in[10];
    const float* b1   = (const float*)d_in[11];
    const float* w2   = (const float*)d_in[12];
    const float* b2   = (const float*)d_in[13];
    const float* w3   = (const float*)d_in[14];
    const float* b3   = (const float*)d_in[15];
    const float* fc1w = (const float*)d_in[16];
    const float* fc1b = (const float*)d_in[17];
    const float* gam  = (const float*)d_in[18];
    const float* bet  = (const float*)d_in[19];
    const float* fc2w = (const float*)d_in[20];
    const float* fc2b = (const float*)d_in[21];
    float* out = (float*)d_out;

    const size_t S1 = 4096 * 128;    // 524288  (layer-1 basis slot)
    const size_t S2 = 1024 * 4096;   // 4194304 (layer-2 basis slot / pool1)
    const size_t S3 = 256 * 8192;    // 2097152 (layer-3 basis slot / pool2 / acc3)

    // choose layer-2 chunk by workspace size (ring needs CK>=3)
    size_t need5 = (25 * S1 + S2 + 5 * S2 + S3) * sizeof(float);
    int CK2 = (ws_size >= need5) ? 5 : 3;
    const int CK3 = 4;

    float* ws = (float*)d_ws;
    float* basis1 = ws;                           // 25 slots
    float* pool1  = basis1 + 25 * S1;             // (1024, 32*128)
    float* basis2 = pool1 + S2;                   // CK2 slots
    float* pool2  = basis2 + (size_t)CK2 * S2;    // (256, 64*128)
    // aliases (regions dead by the time these are written):
    float* acc2   = basis1;                       // 1024*64*128 = 8388608 <= 25*S1
    float* basis3 = basis2;                       // CK3*S3 = 8388608 <= CK2*S2
    float* acc3   = basis2 + (size_t)CK3 * S3;    // 2097152
    float* part   = acc3 + S3;                    // 8*128*512 = 524288
    float* h      = part + 524288;                // 65536
    float* mv     = h + 65536;                    // 1024

    // ---------------- Layer 1: V=4096, Fin=1, Fout=32, full basis ----------------
    k_transpose_x<<<2048, 256, 0, stream>>>(x, basis1);
    for (int k = 1; k < 25; ++k) {
        const float* cur  = basis1 + (size_t)(k - 1) * S1;
        const float* prev = (k >= 2) ? basis1 + (size_t)(k - 2) * S1 : cur;
        float* next = basis1 + (size_t)k * S1;
        k_spmm<7, 0><<<2048, 256, 0, stream>>>(l0cols, l0vals, cur, prev, next, k >= 2 ? 1 : 0);
    }
    k_proj1_pool<<<512, 256, 0, stream>>>(basis1, w1, b1, pool1);

    // ---------------- Layer 2: V=1024, Fin=32, Fout=64, ring CK2 ----------------
    hipMemcpyAsync(basis2, pool1, S2 * sizeof(float), hipMemcpyDeviceToDevice, stream);
    k_init_acc<6><<<8388608 / 256, 256, 0, stream>>>(acc2, b2, 8388608);
    {
        int cs = 0;
        for (int k = 0; k < 25; ++k) {
            if (k >= 1) {
                const float* cur  = basis2 + (size_t)((k - 1) % CK2) * S2;
                const float* prev = basis2 + (size_t)((k >= 2 ? k - 2 : 0) % CK2) * S2;
                float* next = basis2 + (size_t)(k % CK2) * S2;
                k_spmm<12, 1><<<16384, 256, 0, stream>>>(l2cols, l2vals, cur, prev, next, k >= 2 ? 1 : 0);
            }
            if (k - cs + 1 == CK2 || k == 24) {
                k_proj_chunk<32, 64, 64, 5><<<dim3(512, 1), 256, 0, stream>>>(
                    basis2, (long)S2, w2, acc2, cs, k - cs + 1);
                cs = k + 1;
            }
        }
    }
    k_relu_pool<13><<<8192, 256, 0, stream>>>(acc2, pool2);

    // ---------------- Layer 3: V=256, Fin=64, Fout=64, ring CK3=4 ----------------
    hipMemcpyAsync(basis3, pool2, S3 * sizeof(float), hipMemcpyDeviceToDevice, stream);
    k_init_acc<6><<<2097152 / 256, 256, 0, stream>>>(acc3, b3, 2097152);
    {
        int cs = 0;
        for (int k = 0; k < 25; ++k) {
            if (k >= 1) {
                const float* cur  = basis3 + (size_t)((k - 1) % CK3) * S3;
                const float* prev = basis3 + (size_t)((k >= 2 ? k - 2 : 0) % CK3) * S3;
                float* next = basis3 + (size_t)(k % CK3) * S3;
                k_spmm<13, 1><<<8192, 256, 0, stream>>>(l4cols, l4vals, cur, prev, next, k >= 2 ? 1 : 0);
            }
            if (k - cs + 1 == CK3 || k == 24) {
                k_proj_chunk<64, 64, 32, 4><<<dim3(128, 2), 256, 0, stream>>>(
                    basis3, (long)S3, w3, acc3, cs, k - cs + 1);
                cs = k + 1;
            }
        }
    }

    // ---------------- FC1 + BN + FC2 + log_softmax ----------------
    k_fc1_part<<<256, 256, 0, stream>>>(acc3, fc1w, part);
    k_fc1_red<<<256, 256, 0, stream>>>(part, fc1b, h);
    k_bnstats<<<512, 128, 0, stream>>>(h, mv);
    k_head<<<128, 64, 0, stream>>>(h, mv, gam, bet, fc2w, fc2b, out);
}

// Round 2
// 1821.650 us; speedup vs baseline: 1.4474x; 1.4474x over previous
//
#include <hip/hip_runtime.h>

#define B_ 128
#define K_ 25
#define DEG_ 16

#define R8(X) X(0) X(1) X(2) X(3) X(4) X(5) X(6) X(7)
#define R16(X) X(0) X(1) X(2) X(3) X(4) X(5) X(6) X(7) X(8) X(9) X(10) X(11) X(12) X(13) X(14) X(15)

__device__ __forceinline__ float4 f4ma(float t, float4 w, float4 a) {
    a.x = fmaf(t, w.x, a.x); a.y = fmaf(t, w.y, a.y);
    a.z = fmaf(t, w.z, a.z); a.w = fmaf(t, w.w, a.w);
    return a;
}
__device__ __forceinline__ float4 f4max(float4 a, float4 b) {
    return make_float4(fmaxf(a.x, b.x), fmaxf(a.y, b.y), fmaxf(a.z, b.z), fmaxf(a.w, b.w));
}

// ---------------- transpose x: (B=128, N=4096) -> x0 (4096, 128)
__global__ __launch_bounds__(256) void k_transpose_x(const float* __restrict__ x, float* __restrict__ x0) {
    int i = blockIdx.x * 256 + threadIdx.x;   // i = v*128 + b
    int v = i >> 7, b = i & 127;
    x0[i] = x[(b << 12) + v];
}

// ---------------- SpMM step (float4 columns): next = two ? 2*L*cur - prev : L*cur
// L fixed-degree 16/row: row v entries at [16v,16v+16). LOGC4 = log2(C/4).
// SWIZ: XCD column-slab mapping (blockIdx & 7 -> slab) for per-XCD L2 residency.
template<int LOGC4, int SWIZ>
__global__ __launch_bounds__(256) void k_spmm4(const int* __restrict__ cols, const float* __restrict__ vals,
                        const float4* __restrict__ cur, const float4* __restrict__ prev,
                        float4* __restrict__ next, int two) {
    int v, c4;
    if constexpr (SWIZ) {
        constexpr int LOGW4 = LOGC4 - 3;              // f4-columns per XCD slab
        int xcd = blockIdx.x & 7, q = blockIdx.x >> 3;
        int tid = q * 256 + threadIdx.x;
        v = tid >> LOGW4;
        c4 = (xcd << LOGW4) + (tid & ((1 << LOGW4) - 1));
    } else {
        int i = blockIdx.x * 256 + threadIdx.x;
        v = i >> LOGC4;
        c4 = i & ((1 << LOGC4) - 1);
    }
    int base = v * DEG_;
    float4 s = make_float4(0.f, 0.f, 0.f, 0.f);
#pragma unroll
    for (int d = 0; d < DEG_; ++d) {
        float w = vals[base + d];
        float4 xx = cur[((size_t)cols[base + d] << LOGC4) + c4];
        s = f4ma(w, xx, s);
    }
    size_t idx = ((size_t)v << LOGC4) + c4;
    if (two) {
        float4 p = prev[idx];
        s.x = 2.f * s.x - p.x; s.y = 2.f * s.y - p.y;
        s.z = 2.f * s.z - p.z; s.w = 2.f * s.w - p.w;
    }
    next[idx] = s;
}

// ---------------- layer 1 projection (Fin=1, Fout=32) + bias + relu + pool4
// named float4 accumulators (register-guaranteed), W1 (25,32) staged in LDS as float4
__global__ __launch_bounds__(256) void k_proj1_pool(const float* __restrict__ basis,
        const float* __restrict__ W1, const float* __restrict__ b1, float* __restrict__ pool1) {
    __shared__ float4 wl[K_ * 8];
    for (int j = threadIdx.x; j < K_ * 8; j += 256) wl[j] = ((const float4*)W1)[j];
    __syncthreads();
    int i = blockIdx.x * 256 + threadIdx.x;   // i = g*128 + b
    int g = i >> 7, b = i & 127;
#define PJ_DM(j) float4 M##j = make_float4(-1e30f, -1e30f, -1e30f, -1e30f);
    R8(PJ_DM)
#undef PJ_DM
    for (int r = 0; r < 4; ++r) {
        const float* bp = basis + (((size_t)(4 * g + r) << 7) + b);
#define PJ_DC(j) float4 C##j = make_float4(0.f, 0.f, 0.f, 0.f);
        R8(PJ_DC)
#undef PJ_DC
#pragma unroll
        for (int k = 0; k < K_; ++k) {
            float tv = bp[(size_t)k * 524288];
            const float4* w = wl + k * 8;
#define PJ_FM(j) C##j = f4ma(tv, w[j], C##j);
            R8(PJ_FM)
#undef PJ_FM
        }
#define PJ_MX(j) M##j = f4max(M##j, C##j);
        R8(PJ_MX)
#undef PJ_MX
    }
    float* op = pool1 + ((size_t)g << 12) + b;
    const float4* bb = (const float4*)b1;
#define PJ_ST(j) { float4 bj = bb[j]; \
    op[(4*j+0)*128] = fmaxf(M##j.x + bj.x, 0.f); \
    op[(4*j+1)*128] = fmaxf(M##j.y + bj.y, 0.f); \
    op[(4*j+2)*128] = fmaxf(M##j.z + bj.z, 0.f); \
    op[(4*j+3)*128] = fmaxf(M##j.w + bj.w, 0.f); }
    R8(PJ_ST)
#undef PJ_ST
}

// ---------------- layer-2 chunk projection: Fin=32, Fout=64 (all 64 fo per thread, 16 float4)
// acc[v][fo][b] (+)= sum_{kk,fi} basis[kk][v][fi][b] * W[fi*25+k0+kk][fo]
__global__ __launch_bounds__(256) void k_proj_l2(const float* __restrict__ basis, size_t slotStride,
        const float* __restrict__ W, float* __restrict__ acc, int k0, int kcnt, int init,
        const float* __restrict__ bias) {
    __shared__ float4 wl[5 * 32 * 16];
    int total = kcnt * 512;
    for (int j = threadIdx.x; j < total; j += 256) {
        int kk = j >> 9, rem = j & 511;
        int fi = rem >> 4, j4 = rem & 15;
        wl[j] = ((const float4*)(W + (size_t)(fi * K_ + k0 + kk) * 64))[j4];
    }
    __syncthreads();
    int i = blockIdx.x * 256 + threadIdx.x;   // i = v*128 + b, v in [0,1024)
    int v = i >> 7, b = i & 127;
    float* ap = acc + ((size_t)v << 13) + b;
    const float4* bb = (const float4*)bias;
#define L2_DA(j) float4 A##j;
    R16(L2_DA)
#undef L2_DA
    if (init) {
#define L2_IN(j) A##j = bb[j];
        R16(L2_IN)
#undef L2_IN
    } else {
#define L2_LD(j) A##j = make_float4(ap[(4*j+0)*128], ap[(4*j+1)*128], ap[(4*j+2)*128], ap[(4*j+3)*128]);
        R16(L2_LD)
#undef L2_LD
    }
    const float* bp0 = basis + ((size_t)v << 12) + b;
    for (int kk = 0; kk < kcnt; ++kk) {
        const float* bp = bp0 + (size_t)kk * slotStride;
        const float4* wk = wl + (kk << 9);
#pragma unroll 4
        for (int fi = 0; fi < 32; ++fi) {
            float tv = bp[fi << 7];
            const float4* w = wk + (fi << 4);
#define L2_FM(j) A##j = f4ma(tv, w[j], A##j);
            R16(L2_FM)
#undef L2_FM
        }
    }
#define L2_ST(j) ap[(4*j+0)*128] = A##j.x; ap[(4*j+1)*128] = A##j.y; \
                 ap[(4*j+2)*128] = A##j.z; ap[(4*j+3)*128] = A##j.w;
    R16(L2_ST)
#undef L2_ST
}

// ---------------- layer-3 chunk projection: Fin=64, Fout=64 in 2 slices of 32 (grid.y)
__global__ __launch_bounds__(256) void k_proj_l3(const float* __restrict__ basis, size_t slotStride,
        const float* __restrict__ W, float* __restrict__ acc, int k0, int kcnt, int init,
        const float* __restrict__ bias) {
    __shared__ float4 wl[4 * 64 * 8];
    int fo0 = blockIdx.y << 5;
    int total = kcnt * 512;
    for (int j = threadIdx.x; j < total; j += 256) {
        int kk = j >> 9, rem = j & 511;
        int fi = rem >> 3, j4 = rem & 7;
        wl[j] = ((const float4*)(W + (size_t)(fi * K_ + k0 + kk) * 64 + fo0))[j4];
    }
    __syncthreads();
    int i = blockIdx.x * 256 + threadIdx.x;   // i = v*128 + b, v in [0,256)
    int v = i >> 7, b = i & 127;
    float* ap = acc + ((size_t)v << 13) + ((size_t)fo0 << 7) + b;
    const float4* bb = (const float4*)(bias + fo0);
#define L3_DA(j) float4 A##j;
    R8(L3_DA)
#undef L3_DA
    if (init) {
#define L3_IN(j) A##j = bb[j];
        R8(L3_IN)
#undef L3_IN
    } else {
#define L3_LD(j) A##j = make_float4(ap[(4*j+0)*128], ap[(4*j+1)*128], ap[(4*j+2)*128], ap[(4*j+3)*128]);
        R8(L3_LD)
#undef L3_LD
    }
    const float* bp0 = basis + ((size_t)v << 13) + b;
    for (int kk = 0; kk < kcnt; ++kk) {
        const float* bp = bp0 + (size_t)kk * slotStride;
        const float4* wk = wl + (kk << 9);
#pragma unroll 4
        for (int fi = 0; fi < 64; ++fi) {
            float tv = bp[fi << 7];
            const float4* w = wk + (fi << 3);
#define L3_FM(j) A##j = f4ma(tv, w[j], A##j);
            R8(L3_FM)
#undef L3_FM
        }
    }
#define L3_ST(j) ap[(4*j+0)*128] = A##j.x; ap[(4*j+1)*128] = A##j.y; \
                 ap[(4*j+2)*128] = A##j.z; ap[(4*j+3)*128] = A##j.w;
    R8(L3_ST)
#undef L3_ST
}

// ---------------- relu + pool4 over nodes
template<int LOGFB>
__global__ __launch_bounds__(256) void k_relu_pool(const float* __restrict__ acc, float* __restrict__ pool) {
    int i = blockIdx.x * 256 + threadIdx.x;
    int g = i >> LOGFB, rem = i & ((1 << LOGFB) - 1);
    float m = 0.f;
#pragma unroll
    for (int r = 0; r < 4; ++r) m = fmaxf(m, acc[((size_t)(4 * g + r) << LOGFB) + rem]);
    pool[i] = m;
}

// ---------------- FC1 partials: rowsplit 8, 8 b's per thread
__global__ __launch_bounds__(256) void k_fc1_part(const float* __restrict__ t3, const float* __restrict__ w,
                           float* __restrict__ part) {
    int T = blockIdx.x * 256 + threadIdx.x;   // 65536 threads
    int j = T & 511;
    int bg = (T >> 9) & 15;
    int rs = T >> 13;                          // 0..7
    int b0 = bg << 3;
    float a0=0.f,a1=0.f,a2=0.f,a3=0.f,a4=0.f,a5=0.f,a6=0.f,a7=0.f;
    int r0 = rs << 11;
    for (int row = r0; row < r0 + 2048; ++row) {
        float wv = w[(size_t)row * 512 + j];
        const float* tp = t3 + (size_t)row * B_ + b0;
        a0 = fmaf(fmaxf(tp[0], 0.f), wv, a0);
        a1 = fmaf(fmaxf(tp[1], 0.f), wv, a1);
        a2 = fmaf(fmaxf(tp[2], 0.f), wv, a2);
        a3 = fmaf(fmaxf(tp[3], 0.f), wv, a3);
        a4 = fmaf(fmaxf(tp[4], 0.f), wv, a4);
        a5 = fmaf(fmaxf(tp[5], 0.f), wv, a5);
        a6 = fmaf(fmaxf(tp[6], 0.f), wv, a6);
        a7 = fmaf(fmaxf(tp[7], 0.f), wv, a7);
    }
    float* pp = part + ((size_t)rs * B_ + b0) * 512 + j;
    pp[0*512]=a0; pp[1*512]=a1; pp[2*512]=a2; pp[3*512]=a3;
    pp[4*512]=a4; pp[5*512]=a5; pp[6*512]=a6; pp[7*512]=a7;
}

__global__ __launch_bounds__(256) void k_fc1_red(const float* __restrict__ part, const float* __restrict__ bias,
                          float* __restrict__ h) {
    int i = blockIdx.x * 256 + threadIdx.x;   // i = b*512 + j
    float a = bias[i & 511];
#pragma unroll
    for (int rs = 0; rs < 8; ++rs) a += part[((size_t)rs << 16) + i];
    h[i] = a;
}

// ---------------- batchnorm stats over batch (biased var), store mean | inv_std
__global__ void k_bnstats(const float* __restrict__ h, float* __restrict__ mv) {
    __shared__ float s1[128], s2[128];
    int j = blockIdx.x, t = threadIdx.x;
    float v = h[(size_t)t * 512 + j];
    s1[t] = v; s2[t] = v * v;
    __syncthreads();
    for (int o = 64; o > 0; o >>= 1) {
        if (t < o) { s1[t] += s1[t + o]; s2[t] += s2[t + o]; }
        __syncthreads();
    }
    if (t == 0) {
        float m = s1[0] * (1.f / 128.f);
        float var = s2[0] * (1.f / 128.f) - m * m;
        mv[j] = m;
        mv[512 + j] = rsqrtf(var + 1e-5f);
    }
}

// ---------------- BN apply + relu + FC2 + log_softmax, one block per batch row
__global__ void k_head(const float* __restrict__ h, const float* __restrict__ mv,
                       const float* __restrict__ gamma, const float* __restrict__ beta,
                       const float* __restrict__ w2, const float* __restrict__ b2,
                       float* __restrict__ out) {
    __shared__ float hr[512];
    __shared__ float lg[16];
    int b = blockIdx.x, t = threadIdx.x;   // 64 threads
    for (int j = t; j < 512; j += 64) {
        float x = (h[(size_t)b * 512 + j] - mv[j]) * mv[512 + j] * gamma[j] + beta[j];
        hr[j] = fmaxf(x, 0.f);
    }
    __syncthreads();
    if (t < 10) {
        float a = b2[t];
        for (int j = 0; j < 512; ++j) a += hr[j] * w2[j * 10 + t];
        lg[t] = a;
    }
    __syncthreads();
    if (t == 0) {
        float mx = -1e30f;
        for (int q = 0; q < 10; ++q) mx = fmaxf(mx, lg[q]);
        float sum = 0.f;
        for (int q = 0; q < 10; ++q) sum += expf(lg[q] - mx);
        float ls = logf(sum) + mx;
        for (int q = 0; q < 10; ++q) out[b * 10 + q] = lg[q] - ls;
    }
}

extern "C" void kernel_launch(void* const* d_in, const int* in_sizes, int n_in,
                              void* d_out, int out_size, void* d_ws, size_t ws_size,
                              hipStream_t stream) {
    (void)in_sizes; (void)n_in; (void)out_size;
    const float* x      = (const float*)d_in[0];
    const int*   l0cols = (const int*)d_in[2];
    const float* l0vals = (const float*)d_in[3];
    const int*   l2cols = (const int*)d_in[5];
    const float* l2vals = (const float*)d_in[6];
    const int*   l4cols = (const int*)d_in[8];
    const float* l4vals = (const float*)d_in[9];
    const float* w1   = (const float*)d_in[10];
    const float* b1   = (const float*)d_in[11];
    const float* w2   = (const float*)d_in[12];
    const float* b2   = (const float*)d_in[13];
    const float* w3   = (const float*)d_in[14];
    const float* b3   = (const float*)d_in[15];
    const float* fc1w = (const float*)d_in[16];
    const float* fc1b = (const float*)d_in[17];
    const float* gam  = (const float*)d_in[18];
    const float* bet  = (const float*)d_in[19];
    const float* fc2w = (const float*)d_in[20];
    const float* fc2b = (const float*)d_in[21];
    float* out = (float*)d_out;

    const size_t S1 = 4096 * 128;    // layer-1 basis slot
    const size_t S2 = 1024 * 4096;   // layer-2 basis slot (= pool1 size)
    const size_t S3 = 256 * 8192;    // layer-3 basis slot (= pool2 / acc3 size)

    const size_t tailN = 8 * 128 * 512 + 128 * 512 + 1024;
    size_t need5 = (25 * S1 + 5 * S2 + tailN) * sizeof(float);
    int CK2 = (ws_size >= need5) ? 5 : 3;
    const int CK3 = 4;

    float* ws = (float*)d_ws;
    float* basis1 = ws;                              // 25 slots of S1
    float* basis2 = ws + 25 * S1;                    // ring CK2 slots; slot0 doubles as pool1
    float* acc2   = basis1;                          // alias: 8.39M <= 13.1M, basis1 dead
    float* basis3 = basis2;                          // ring CK3 slots; slot0 doubles as pool2
    float* acc3   = basis2 + (size_t)CK3 * S3;       // within old basis2 region
    float* tail   = basis2 + (size_t)CK2 * S2;
    float* part   = tail;                            // 8*128*512
    float* h      = part + 8 * 128 * 512;            // 65536
    float* mv     = h + 65536;                       // 1024

    // ---------------- Layer 1: V=4096, C=128 (f4: 32), full basis ----------------
    k_transpose_x<<<2048, 256, 0, stream>>>(x, basis1);
    for (int k = 1; k < 25; ++k) {
        const float* cur  = basis1 + (size_t)(k - 1) * S1;
        const float* prev = (k >= 2) ? basis1 + (size_t)(k - 2) * S1 : cur;
        float* next = basis1 + (size_t)k * S1;
        k_spmm4<5, 0><<<512, 256, 0, stream>>>(l0cols, l0vals, (const float4*)cur,
                                               (const float4*)prev, (float4*)next, k >= 2 ? 1 : 0);
    }
    k_proj1_pool<<<512, 256, 0, stream>>>(basis1, w1, b1, basis2 /*pool1 = slot0*/);

    // ---------------- Layer 2: V=1024, C=4096 (f4: 1024), ring CK2 ----------------
    {
        int cs = 0;
        for (int k = 0; k < 25; ++k) {
            if (k >= 1) {
                const float* cur  = basis2 + (size_t)((k - 1) % CK2) * S2;
                const float* prev = basis2 + (size_t)((k >= 2 ? k - 2 : 0) % CK2) * S2;
                float* next = basis2 + (size_t)(k % CK2) * S2;
                k_spmm4<10, 1><<<4096, 256, 0, stream>>>(l2cols, l2vals, (const float4*)cur,
                                                         (const float4*)prev, (float4*)next, k >= 2 ? 1 : 0);
            }
            if (k - cs + 1 == CK2 || k == 24) {
                k_proj_l2<<<512, 256, 0, stream>>>(basis2, S2, w2, acc2, cs, k - cs + 1,
                                                   cs == 0 ? 1 : 0, b2);
                cs = k + 1;
            }
        }
    }
    k_relu_pool<13><<<8192, 256, 0, stream>>>(acc2, basis3 /*pool2 = slot0*/);

    // ---------------- Layer 3: V=256, C=8192 (f4: 2048), ring CK3=4 ----------------
    {
        int cs = 0;
        for (int k = 0; k < 25; ++k) {
            if (k >= 1) {
                const float* cur  = basis3 + (size_t)((k - 1) % CK3) * S3;
                const float* prev = basis3 + (size_t)((k >= 2 ? k - 2 : 0) % CK3) * S3;
                float* next = basis3 + (size_t)(k % CK3) * S3;
                k_spmm4<11, 1><<<2048, 256, 0, stream>>>(l4cols, l4vals, (const float4*)cur,
                                                         (const float4*)prev, (float4*)next, k >= 2 ? 1 : 0);
            }
            if (k - cs + 1 == CK3 || k == 24) {
                k_proj_l3<<<dim3(128, 2), 256, 0, stream>>>(basis3, S3, w3, acc3, cs, k - cs + 1,
                                                            cs == 0 ? 1 : 0, b3);
                cs = k + 1;
            }
        }
    }

    // ---------------- FC1 + BN + FC2 + log_softmax ----------------
    k_fc1_part<<<256, 256, 0, stream>>>(acc3, fc1w, part);
    k_fc1_red<<<256, 256, 0, stream>>>(part, fc1b, h);
    k_bnstats<<<512, 128, 0, stream>>>(h, mv);
    k_head<<<128, 64, 0, stream>>>(h, mv, gam, bet, fc2w, fc2b, out);
}

// Round 3
// 1397.008 us; speedup vs baseline: 1.8874x; 1.3040x over previous
//
#include <hip/hip_runtime.h>

#define B_ 128
#define K_ 25
#define DEG_ 16

#define R4(X) X(0) X(1) X(2) X(3)
#define R8(X) X(0) X(1) X(2) X(3) X(4) X(5) X(6) X(7)
#define R16(X) X(0) X(1) X(2) X(3) X(4) X(5) X(6) X(7) X(8) X(9) X(10) X(11) X(12) X(13) X(14) X(15)

__device__ __forceinline__ float4 f4ma(float t, float4 w, float4 a) {
    a.x = fmaf(t, w.x, a.x); a.y = fmaf(t, w.y, a.y);
    a.z = fmaf(t, w.z, a.z); a.w = fmaf(t, w.w, a.w);
    return a;
}
__device__ __forceinline__ float4 f4max(float4 a, float4 b) {
    return make_float4(fmaxf(a.x, b.x), fmaxf(a.y, b.y), fmaxf(a.z, b.z), fmaxf(a.w, b.w));
}

// ---------------- transpose x: (B=128, N=4096) -> x0 (4096, 128)
__global__ __launch_bounds__(256) void k_transpose_x(const float* __restrict__ x, float* __restrict__ x0) {
    int i = blockIdx.x * 256 + threadIdx.x;   // i = v*128 + b
    int v = i >> 7, b = i & 127;
    x0[i] = x[(b << 12) + v];
}

// ---------------- layer-1 SpMM: one wave per row v, lane = float2 column (C=128 -> 64 f2)
// cols/vals wave-uniform -> s_load broadcast
__global__ __launch_bounds__(256) void k_spmm1(const int* __restrict__ cols, const float* __restrict__ vals,
        const float2* __restrict__ cur, const float2* __restrict__ prev,
        float2* __restrict__ next, int two) {
    int t = blockIdx.x * 256 + threadIdx.x;
    int v = __builtin_amdgcn_readfirstlane(t >> 6);
    int lane = threadIdx.x & 63;
    int base = v * DEG_;
    float2 s = make_float2(0.f, 0.f);
#pragma unroll
    for (int d = 0; d < DEG_; ++d) {
        float wv = vals[base + d];
        float2 xx = cur[((size_t)cols[base + d] << 6) + lane];
        s.x = fmaf(wv, xx.x, s.x); s.y = fmaf(wv, xx.y, s.y);
    }
    size_t idx = ((size_t)v << 6) + lane;
    if (two) {
        float2 p = prev[idx];
        s.x = 2.f * s.x - p.x; s.y = 2.f * s.y - p.y;
    }
    next[idx] = s;
}

// ---------------- SpMM (layers 2/3, float4 columns, XCD slab swizzle, wave-uniform row)
// LOGC4 = log2(C/4); LOGW4 = LOGC4-3 >= 6 so v is wave-uniform.
template<int LOGC4>
__global__ __launch_bounds__(256) void k_spmm4(const int* __restrict__ cols, const float* __restrict__ vals,
                        const float4* __restrict__ cur, const float4* __restrict__ prev,
                        float4* __restrict__ next, int two) {
    constexpr int LOGW4 = LOGC4 - 3;
    int xcd = blockIdx.x & 7, q = blockIdx.x >> 3;
    int tid = q * 256 + threadIdx.x;
    int v = __builtin_amdgcn_readfirstlane(tid >> LOGW4);
    int c4 = (xcd << LOGW4) + (tid & ((1 << LOGW4) - 1));
    int base = v * DEG_;
    float4 s = make_float4(0.f, 0.f, 0.f, 0.f);
#pragma unroll
    for (int d = 0; d < DEG_; ++d) {
        float w = vals[base + d];
        float4 xx = cur[((size_t)cols[base + d] << LOGC4) + c4];
        s = f4ma(w, xx, s);
    }
    size_t idx = ((size_t)v << LOGC4) + c4;
    if (two) {
        float4 p = prev[idx];
        s.x = 2.f * s.x - p.x; s.y = 2.f * s.y - p.y;
        s.z = 2.f * s.z - p.z; s.w = 2.f * s.w - p.w;
    }
    next[idx] = s;
}

// ---------------- layer 1 projection (Fin=1, Fout=32) + bias + relu + pool4
// grid (512, 2): blockIdx.y = fo-half (16 fo/thread). W read wave-uniform (s_load).
__global__ __launch_bounds__(256) void k_proj1_pool(const float* __restrict__ basis,
        const float* __restrict__ W1, const float* __restrict__ b1, float* __restrict__ pool1) {
    int half = blockIdx.y;
    int i = blockIdx.x * 256 + threadIdx.x;   // i = g*128 + b
    int g = i >> 7, b = i & 127;
    const float* wbase = W1 + half * 16;      // row k at wbase + k*32, 16 floats
#define P1_DM(j) float4 M##j = make_float4(-1e30f, -1e30f, -1e30f, -1e30f);
    R4(P1_DM)
#undef P1_DM
    for (int r = 0; r < 4; ++r) {
        const float* bp = basis + (((size_t)(4 * g + r) << 7) + b);
#define P1_DC(j) float4 C##j = make_float4(0.f, 0.f, 0.f, 0.f);
        R4(P1_DC)
#undef P1_DC
#pragma unroll 5
        for (int k = 0; k < K_; ++k) {
            float tv = bp[(size_t)k * 524288];
            const float4* w = (const float4*)(wbase + k * 32);
#define P1_FM(j) C##j = f4ma(tv, w[j], C##j);
            R4(P1_FM)
#undef P1_FM
        }
#define P1_MX(j) M##j = f4max(M##j, C##j);
        R4(P1_MX)
#undef P1_MX
    }
    float* op = pool1 + ((size_t)g << 12) + ((size_t)half << 11) + b;
    const float* bb = b1 + half * 16;
#define P1_ST(j) \
    op[(4*j+0)*128] = fmaxf(M##j.x + bb[4*j+0], 0.f); \
    op[(4*j+1)*128] = fmaxf(M##j.y + bb[4*j+1], 0.f); \
    op[(4*j+2)*128] = fmaxf(M##j.z + bb[4*j+2], 0.f); \
    op[(4*j+3)*128] = fmaxf(M##j.w + bb[4*j+3], 0.f);
    R4(P1_ST)
#undef P1_ST
}

// ---------------- layer-2 chunk projection: Fin=32, Fout=64 (64 fo/thread), W via s_load
__global__ __launch_bounds__(256) void k_proj_l2(const float* __restrict__ basis, size_t slotStride,
        const float* __restrict__ W, float* __restrict__ acc, int k0, int kcnt, int init,
        const float* __restrict__ bias) {
    int i = blockIdx.x * 256 + threadIdx.x;   // i = v*128 + b, v in [0,1024)
    int v = i >> 7, b = i & 127;
    float* ap = acc + ((size_t)v << 13) + b;
#define L2_DA(j) float4 A##j;
    R16(L2_DA)
#undef L2_DA
    if (init) {
#define L2_IN(j) A##j = make_float4(bias[4*j+0], bias[4*j+1], bias[4*j+2], bias[4*j+3]);
        R16(L2_IN)
#undef L2_IN
    } else {
#define L2_LD(j) A##j = make_float4(ap[(4*j+0)*128], ap[(4*j+1)*128], ap[(4*j+2)*128], ap[(4*j+3)*128]);
        R16(L2_LD)
#undef L2_LD
    }
    const float* bp0 = basis + ((size_t)v << 12) + b;
    for (int kk = 0; kk < kcnt; ++kk) {
        const float* bp = bp0 + (size_t)kk * slotStride;
        const float* wk = W + (size_t)(k0 + kk) * 64;
#pragma unroll 4
        for (int fi = 0; fi < 32; ++fi) {
            float tv = bp[fi << 7];
            const float4* w = (const float4*)(wk + (size_t)fi * (K_ * 64));
#define L2_FM(j) A##j = f4ma(tv, w[j], A##j);
            R16(L2_FM)
#undef L2_FM
        }
    }
#define L2_ST(j) ap[(4*j+0)*128] = A##j.x; ap[(4*j+1)*128] = A##j.y; \
                 ap[(4*j+2)*128] = A##j.z; ap[(4*j+3)*128] = A##j.w;
    R16(L2_ST)
#undef L2_ST
}

// ---------------- layer-3 chunk projection: Fin=64, Fout=64 in 4 slices of 16 (grid.y)
__global__ __launch_bounds__(256) void k_proj_l3(const float* __restrict__ basis, size_t slotStride,
        const float* __restrict__ W, float* __restrict__ acc, int k0, int kcnt, int init,
        const float* __restrict__ bias) {
    int fo0 = blockIdx.y << 4;
    int i = blockIdx.x * 256 + threadIdx.x;   // i = v*128 + b, v in [0,256)
    int v = i >> 7, b = i & 127;
    float* ap = acc + ((size_t)v << 13) + ((size_t)fo0 << 7) + b;
    const float* bb = bias + fo0;
#define L3_DA(j) float4 A##j;
    R4(L3_DA)
#undef L3_DA
    if (init) {
#define L3_IN(j) A##j = make_float4(bb[4*j+0], bb[4*j+1], bb[4*j+2], bb[4*j+3]);
        R4(L3_IN)
#undef L3_IN
    } else {
#define L3_LD(j) A##j = make_float4(ap[(4*j+0)*128], ap[(4*j+1)*128], ap[(4*j+2)*128], ap[(4*j+3)*128]);
        R4(L3_LD)
#undef L3_LD
    }
    const float* bp0 = basis + ((size_t)v << 13) + b;
    for (int kk = 0; kk < kcnt; ++kk) {
        const float* bp = bp0 + (size_t)kk * slotStride;
        const float* wk = W + (size_t)(k0 + kk) * 64 + fo0;
#pragma unroll 4
        for (int fi = 0; fi < 64; ++fi) {
            float tv = bp[fi << 7];
            const float4* w = (const float4*)(wk + (size_t)fi * (K_ * 64));
#define L3_FM(j) A##j = f4ma(tv, w[j], A##j);
            R4(L3_FM)
#undef L3_FM
        }
    }
#define L3_ST(j) ap[(4*j+0)*128] = A##j.x; ap[(4*j+1)*128] = A##j.y; \
                 ap[(4*j+2)*128] = A##j.z; ap[(4*j+3)*128] = A##j.w;
    R4(L3_ST)
#undef L3_ST
}

// ---------------- relu + pool4 over nodes
template<int LOGFB>
__global__ __launch_bounds__(256) void k_relu_pool(const float* __restrict__ acc, float* __restrict__ pool) {
    int i = blockIdx.x * 256 + threadIdx.x;
    int g = i >> LOGFB, rem = i & ((1 << LOGFB) - 1);
    float m = 0.f;
#pragma unroll
    for (int r = 0; r < 4; ++r) m = fmaxf(m, acc[((size_t)(4 * g + r) << LOGFB) + rem]);
    pool[i] = m;
}

// ---------------- FC1 partials: rowsplit 8, 8 b's per thread (t3 via float4)
__global__ __launch_bounds__(256) void k_fc1_part(const float* __restrict__ t3, const float* __restrict__ w,
                           float* __restrict__ part) {
    int T = blockIdx.x * 256 + threadIdx.x;   // 65536 threads
    int j = T & 511;
    int bg = (T >> 9) & 15;
    int rs = T >> 13;                          // 0..7
    int b0 = bg << 3;
    float a0=0.f,a1=0.f,a2=0.f,a3=0.f,a4=0.f,a5=0.f,a6=0.f,a7=0.f;
    int r0 = rs << 11;
    for (int row = r0; row < r0 + 2048; ++row) {
        float wv = w[(size_t)row * 512 + j];
        const float4* tp = (const float4*)(t3 + (size_t)row * B_ + b0);
        float4 t0 = tp[0], t1 = tp[1];
        a0 = fmaf(fmaxf(t0.x, 0.f), wv, a0);
        a1 = fmaf(fmaxf(t0.y, 0.f), wv, a1);
        a2 = fmaf(fmaxf(t0.z, 0.f), wv, a2);
        a3 = fmaf(fmaxf(t0.w, 0.f), wv, a3);
        a4 = fmaf(fmaxf(t1.x, 0.f), wv, a4);
        a5 = fmaf(fmaxf(t1.y, 0.f), wv, a5);
        a6 = fmaf(fmaxf(t1.z, 0.f), wv, a6);
        a7 = fmaf(fmaxf(t1.w, 0.f), wv, a7);
    }
    float* pp = part + ((size_t)rs * B_ + b0) * 512 + j;
    pp[0*512]=a0; pp[1*512]=a1; pp[2*512]=a2; pp[3*512]=a3;
    pp[4*512]=a4; pp[5*512]=a5; pp[6*512]=a6; pp[7*512]=a7;
}

__global__ __launch_bounds__(256) void k_fc1_red(const float* __restrict__ part, const float* __restrict__ bias,
                          float* __restrict__ h) {
    int i = blockIdx.x * 256 + threadIdx.x;   // i = b*512 + j
    float a = bias[i & 511];
#pragma unroll
    for (int rs = 0; rs < 8; ++rs) a += part[((size_t)rs << 16) + i];
    h[i] = a;
}

// ---------------- batchnorm stats over batch (biased var), store mean | inv_std
__global__ void k_bnstats(const float* __restrict__ h, float* __restrict__ mv) {
    __shared__ float s1[128], s2[128];
    int j = blockIdx.x, t = threadIdx.x;
    float v = h[(size_t)t * 512 + j];
    s1[t] = v; s2[t] = v * v;
    __syncthreads();
    for (int o = 64; o > 0; o >>= 1) {
        if (t < o) { s1[t] += s1[t + o]; s2[t] += s2[t + o]; }
        __syncthreads();
    }
    if (t == 0) {
        float m = s1[0] * (1.f / 128.f);
        float var = s2[0] * (1.f / 128.f) - m * m;
        mv[j] = m;
        mv[512 + j] = rsqrtf(var + 1e-5f);
    }
}

// ---------------- BN apply + relu + FC2 + log_softmax, one block per batch row
__global__ void k_head(const float* __restrict__ h, const float* __restrict__ mv,
                       const float* __restrict__ gamma, const float* __restrict__ beta,
                       const float* __restrict__ w2, const float* __restrict__ b2,
                       float* __restrict__ out) {
    __shared__ float hr[512];
    __shared__ float lg[16];
    int b = blockIdx.x, t = threadIdx.x;   // 64 threads
    for (int j = t; j < 512; j += 64) {
        float x = (h[(size_t)b * 512 + j] - mv[j]) * mv[512 + j] * gamma[j] + beta[j];
        hr[j] = fmaxf(x, 0.f);
    }
    __syncthreads();
    if (t < 10) {
        float a = b2[t];
        for (int j = 0; j < 512; ++j) a += hr[j] * w2[j * 10 + t];
        lg[t] = a;
    }
    __syncthreads();
    if (t == 0) {
        float mx = -1e30f;
        for (int q = 0; q < 10; ++q) mx = fmaxf(mx, lg[q]);
        float sum = 0.f;
        for (int q = 0; q < 10; ++q) sum += expf(lg[q] - mx);
        float ls = logf(sum) + mx;
        for (int q = 0; q < 10; ++q) out[b * 10 + q] = lg[q] - ls;
    }
}

extern "C" void kernel_launch(void* const* d_in, const int* in_sizes, int n_in,
                              void* d_out, int out_size, void* d_ws, size_t ws_size,
                              hipStream_t stream) {
    (void)in_sizes; (void)n_in; (void)out_size;
    const float* x      = (const float*)d_in[0];
    const int*   l0cols = (const int*)d_in[2];
    const float* l0vals = (const float*)d_in[3];
    const int*   l2cols = (const int*)d_in[5];
    const float* l2vals = (const float*)d_in[6];
    const int*   l4cols = (const int*)d_in[8];
    const float* l4vals = (const float*)d_in[9];
    const float* w1   = (const float*)d_in[10];
    const float* b1   = (const float*)d_in[11];
    const float* w2   = (const float*)d_in[12];
    const float* b2   = (const float*)d_in[13];
    const float* w3   = (const float*)d_in[14];
    const float* b3   = (const float*)d_in[15];
    const float* fc1w = (const float*)d_in[16];
    const float* fc1b = (const float*)d_in[17];
    const float* gam  = (const float*)d_in[18];
    const float* bet  = (const float*)d_in[19];
    const float* fc2w = (const float*)d_in[20];
    const float* fc2b = (const float*)d_in[21];
    float* out = (float*)d_out;

    const size_t S1 = 4096 * 128;    // layer-1 basis slot
    const size_t S2 = 1024 * 4096;   // layer-2 basis slot (= pool1 size)
    const size_t S3 = 256 * 8192;    // layer-3 basis slot (= pool2 / acc3 size)

    const size_t tailN = 8 * 128 * 512 + 128 * 512 + 1024;
    size_t need5 = (25 * S1 + 5 * S2 + tailN) * sizeof(float);
    int CK2 = (ws_size >= need5) ? 5 : 3;
    const int CK3 = 4;

    float* ws = (float*)d_ws;
    float* basis1 = ws;                              // 25 slots of S1
    float* basis2 = ws + 25 * S1;                    // ring CK2 slots; slot0 doubles as pool1
    float* acc2   = basis1;                          // alias: basis1 dead after proj1
    float* basis3 = basis2;                          // ring CK3 slots; slot0 doubles as pool2
    float* acc3   = basis2 + (size_t)CK3 * S3;       // beyond basis3 ring
    float* tail   = basis2 + (size_t)CK2 * S2;
    float* part   = tail;                            // 8*128*512
    float* h      = part + 8 * 128 * 512;            // 65536
    float* mv     = h + 65536;                       // 1024

    // ---------------- Layer 1: V=4096, C=128, full basis ----------------
    k_transpose_x<<<2048, 256, 0, stream>>>(x, basis1);
    for (int k = 1; k < 25; ++k) {
        const float* cur  = basis1 + (size_t)(k - 1) * S1;
        const float* prev = (k >= 2) ? basis1 + (size_t)(k - 2) * S1 : cur;
        float* next = basis1 + (size_t)k * S1;
        k_spmm1<<<1024, 256, 0, stream>>>(l0cols, l0vals, (const float2*)cur,
                                          (const float2*)prev, (float2*)next, k >= 2 ? 1 : 0);
    }
    k_proj1_pool<<<dim3(512, 2), 256, 0, stream>>>(basis1, w1, b1, basis2 /*pool1 = slot0*/);

    // ---------------- Layer 2: V=1024, C=4096, ring CK2 ----------------
    {
        int cs = 0;
        for (int k = 0; k < 25; ++k) {
            if (k >= 1) {
                const float* cur  = basis2 + (size_t)((k - 1) % CK2) * S2;
                const float* prev = basis2 + (size_t)((k >= 2 ? k - 2 : 0) % CK2) * S2;
                float* next = basis2 + (size_t)(k % CK2) * S2;
                k_spmm4<10><<<4096, 256, 0, stream>>>(l2cols, l2vals, (const float4*)cur,
                                                      (const float4*)prev, (float4*)next, k >= 2 ? 1 : 0);
            }
            if (k - cs + 1 == CK2 || k == 24) {
                k_proj_l2<<<512, 256, 0, stream>>>(basis2, S2, w2, acc2, cs, k - cs + 1,
                                                   cs == 0 ? 1 : 0, b2);
                cs = k + 1;
            }
        }
    }
    k_relu_pool<13><<<8192, 256, 0, stream>>>(acc2, basis3 /*pool2 = slot0*/);

    // ---------------- Layer 3: V=256, C=8192, ring CK3=4 ----------------
    {
        int cs = 0;
        for (int k = 0; k < 25; ++k) {
            if (k >= 1) {
                const float* cur  = basis3 + (size_t)((k - 1) % CK3) * S3;
                const float* prev = basis3 + (size_t)((k >= 2 ? k - 2 : 0) % CK3) * S3;
                float* next = basis3 + (size_t)(k % CK3) * S3;
                k_spmm4<11><<<2048, 256, 0, stream>>>(l4cols, l4vals, (const float4*)cur,
                                                      (const float4*)prev, (float4*)next, k >= 2 ? 1 : 0);
            }
            if (k - cs + 1 == CK3 || k == 24) {
                k_proj_l3<<<dim3(128, 4), 256, 0, stream>>>(basis3, S3, w3, acc3, cs, k - cs + 1,
                                                            cs == 0 ? 1 : 0, b3);
                cs = k + 1;
            }
        }
    }

    // ---------------- FC1 + BN + FC2 + log_softmax ----------------
    k_fc1_part<<<256, 256, 0, stream>>>(acc3, fc1w, part);
    k_fc1_red<<<256, 256, 0, stream>>>(part, fc1b, h);
    k_bnstats<<<512, 128, 0, stream>>>(h, mv);
    k_head<<<128, 64, 0, stream>>>(h, mv, gam, bet, fc2w, fc2b, out);
}

// Round 4
// 1206.820 us; speedup vs baseline: 2.1848x; 1.1576x over previous
//
#include <hip/hip_runtime.h>

#define B_ 128
#define K_ 25
#define DEG_ 16

#define R4(X) X(0) X(1) X(2) X(3)
#define R8(X) X(0) X(1) X(2) X(3) X(4) X(5) X(6) X(7)
#define R16(X) X(0) X(1) X(2) X(3) X(4) X(5) X(6) X(7) X(8) X(9) X(10) X(11) X(12) X(13) X(14) X(15)

__device__ __forceinline__ float4 f4ma(float t, float4 w, float4 a) {
    a.x = fmaf(t, w.x, a.x); a.y = fmaf(t, w.y, a.y);
    a.z = fmaf(t, w.z, a.z); a.w = fmaf(t, w.w, a.w);
    return a;
}
__device__ __forceinline__ float4 f4max(float4 a, float4 b) {
    return make_float4(fmaxf(a.x, b.x), fmaxf(a.y, b.y), fmaxf(a.z, b.z), fmaxf(a.w, b.w));
}

// ---------------- transpose x: (B=128, N=4096) -> x0 (4096, 128)
__global__ __launch_bounds__(256) void k_transpose_x(const float* __restrict__ x, float* __restrict__ x0) {
    int i = blockIdx.x * 256 + threadIdx.x;   // i = v*128 + b
    int v = i >> 7, b = i & 127;
    x0[i] = x[(b << 12) + v];
}

// ---------------- layer-1 SpMM: one wave per row v, lane = float2 column (C=128 -> 64 f2)
__global__ __launch_bounds__(256) void k_spmm1(const int* __restrict__ cols, const float* __restrict__ vals,
        const float2* __restrict__ cur, const float2* __restrict__ prev,
        float2* __restrict__ next, int two) {
    int t = blockIdx.x * 256 + threadIdx.x;
    int v = __builtin_amdgcn_readfirstlane(t >> 6);
    int lane = threadIdx.x & 63;
    int base = v * DEG_;
    float2 s = make_float2(0.f, 0.f);
#pragma unroll
    for (int d = 0; d < DEG_; ++d) {
        float wv = vals[base + d];
        float2 xx = cur[((size_t)cols[base + d] << 6) + lane];
        s.x = fmaf(wv, xx.x, s.x); s.y = fmaf(wv, xx.y, s.y);
    }
    size_t idx = ((size_t)v << 6) + lane;
    if (two) {
        float2 p = prev[idx];
        s.x = 2.f * s.x - p.x; s.y = 2.f * s.y - p.y;
    }
    next[idx] = s;
}

// ---------------- SpMM (layers 2/3, float4 columns, XCD slab swizzle, wave-uniform row)
template<int LOGC4>
__global__ __launch_bounds__(256) void k_spmm4(const int* __restrict__ cols, const float* __restrict__ vals,
                        const float4* __restrict__ cur, const float4* __restrict__ prev,
                        float4* __restrict__ next, int two) {
    constexpr int LOGW4 = LOGC4 - 3;
    int xcd = blockIdx.x & 7, q = blockIdx.x >> 3;
    int tid = q * 256 + threadIdx.x;
    int v = __builtin_amdgcn_readfirstlane(tid >> LOGW4);
    int c4 = (xcd << LOGW4) + (tid & ((1 << LOGW4) - 1));
    int base = v * DEG_;
    float4 s = make_float4(0.f, 0.f, 0.f, 0.f);
#pragma unroll
    for (int d = 0; d < DEG_; ++d) {
        float w = vals[base + d];
        float4 xx = cur[((size_t)cols[base + d] << LOGC4) + c4];
        s = f4ma(w, xx, s);
    }
    size_t idx = ((size_t)v << LOGC4) + c4;
    if (two) {
        float4 p = prev[idx];
        s.x = 2.f * s.x - p.x; s.y = 2.f * s.y - p.y;
        s.z = 2.f * s.z - p.z; s.w = 2.f * s.w - p.w;
    }
    next[idx] = s;
}

// ---------------- layer 1 projection (Fin=1, Fout=32) + bias + relu + pool4
__global__ __launch_bounds__(256) void k_proj1_pool(const float* __restrict__ basis,
        const float* __restrict__ W1, const float* __restrict__ b1, float* __restrict__ pool1) {
    int half = blockIdx.y;
    int i = blockIdx.x * 256 + threadIdx.x;   // i = g*128 + b
    int g = i >> 7, b = i & 127;
    const float* wbase = W1 + half * 16;
#define P1_DM(j) float4 M##j = make_float4(-1e30f, -1e30f, -1e30f, -1e30f);
    R4(P1_DM)
#undef P1_DM
    for (int r = 0; r < 4; ++r) {
        const float* bp = basis + (((size_t)(4 * g + r) << 7) + b);
#define P1_DC(j) float4 C##j = make_float4(0.f, 0.f, 0.f, 0.f);
        R4(P1_DC)
#undef P1_DC
#pragma unroll 5
        for (int k = 0; k < K_; ++k) {
            float tv = bp[(size_t)k * 524288];
            const float4* w = (const float4*)(wbase + k * 32);
#define P1_FM(j) C##j = f4ma(tv, w[j], C##j);
            R4(P1_FM)
#undef P1_FM
        }
#define P1_MX(j) M##j = f4max(M##j, C##j);
        R4(P1_MX)
#undef P1_MX
    }
    float* op = pool1 + ((size_t)g << 12) + ((size_t)half << 11) + b;
    const float* bb = b1 + half * 16;
#define P1_ST(j) \
    op[(4*j+0)*128] = fmaxf(M##j.x + bb[4*j+0], 0.f); \
    op[(4*j+1)*128] = fmaxf(M##j.y + bb[4*j+1], 0.f); \
    op[(4*j+2)*128] = fmaxf(M##j.z + bb[4*j+2], 0.f); \
    op[(4*j+3)*128] = fmaxf(M##j.w + bb[4*j+3], 0.f);
    R4(P1_ST)
#undef P1_ST
}

// ---------------- layer-2 chunk projection: Fin=32, Fout=64 (64 fo/thread), W via s_load
__global__ __launch_bounds__(256) void k_proj_l2(const float* __restrict__ basis, size_t slotStride,
        const float* __restrict__ W, float* __restrict__ acc, int k0, int kcnt, int init,
        const float* __restrict__ bias) {
    int i = blockIdx.x * 256 + threadIdx.x;   // i = v*128 + b, v in [0,1024)
    int v = i >> 7, b = i & 127;
    float* ap = acc + ((size_t)v << 13) + b;
#define L2_DA(j) float4 A##j;
    R16(L2_DA)
#undef L2_DA
    if (init) {
#define L2_IN(j) A##j = make_float4(bias[4*j+0], bias[4*j+1], bias[4*j+2], bias[4*j+3]);
        R16(L2_IN)
#undef L2_IN
    } else {
#define L2_LD(j) A##j = make_float4(ap[(4*j+0)*128], ap[(4*j+1)*128], ap[(4*j+2)*128], ap[(4*j+3)*128]);
        R16(L2_LD)
#undef L2_LD
    }
    const float* bp0 = basis + ((size_t)v << 12) + b;
    for (int kk = 0; kk < kcnt; ++kk) {
        const float* bp = bp0 + (size_t)kk * slotStride;
        const float* wk = W + (size_t)(k0 + kk) * 64;
#pragma unroll 4
        for (int fi = 0; fi < 32; ++fi) {
            float tv = bp[fi << 7];
            const float4* w = (const float4*)(wk + (size_t)fi * (K_ * 64));
#define L2_FM(j) A##j = f4ma(tv, w[j], A##j);
            R16(L2_FM)
#undef L2_FM
        }
    }
#define L2_ST(j) ap[(4*j+0)*128] = A##j.x; ap[(4*j+1)*128] = A##j.y; \
                 ap[(4*j+2)*128] = A##j.z; ap[(4*j+3)*128] = A##j.w;
    R16(L2_ST)
#undef L2_ST
}

// ---------------- layer-3 chunk projection: Fin=64, Fout=64 in 4 slices of 16 (grid.y)
// finalrelu: last chunk applies ReLU at store (fc1 then reads activated values)
__global__ __launch_bounds__(256) void k_proj_l3(const float* __restrict__ basis, size_t slotStride,
        const float* __restrict__ W, float* __restrict__ acc, int k0, int kcnt, int init,
        const float* __restrict__ bias, int finalrelu) {
    int fo0 = blockIdx.y << 4;
    int i = blockIdx.x * 256 + threadIdx.x;   // i = v*128 + b, v in [0,256)
    int v = i >> 7, b = i & 127;
    float* ap = acc + ((size_t)v << 13) + ((size_t)fo0 << 7) + b;
    const float* bb = bias + fo0;
#define L3_DA(j) float4 A##j;
    R4(L3_DA)
#undef L3_DA
    if (init) {
#define L3_IN(j) A##j = make_float4(bb[4*j+0], bb[4*j+1], bb[4*j+2], bb[4*j+3]);
        R4(L3_IN)
#undef L3_IN
    } else {
#define L3_LD(j) A##j = make_float4(ap[(4*j+0)*128], ap[(4*j+1)*128], ap[(4*j+2)*128], ap[(4*j+3)*128]);
        R4(L3_LD)
#undef L3_LD
    }
    const float* bp0 = basis + ((size_t)v << 13) + b;
    for (int kk = 0; kk < kcnt; ++kk) {
        const float* bp = bp0 + (size_t)kk * slotStride;
        const float* wk = W + (size_t)(k0 + kk) * 64 + fo0;
#pragma unroll 4
        for (int fi = 0; fi < 64; ++fi) {
            float tv = bp[fi << 7];
            const float4* w = (const float4*)(wk + (size_t)fi * (K_ * 64));
#define L3_FM(j) A##j = f4ma(tv, w[j], A##j);
            R4(L3_FM)
#undef L3_FM
        }
    }
    if (finalrelu) {
        float4 z = make_float4(0.f, 0.f, 0.f, 0.f);
#define L3_RL(j) A##j = f4max(A##j, z);
        R4(L3_RL)
#undef L3_RL
    }
#define L3_ST(j) ap[(4*j+0)*128] = A##j.x; ap[(4*j+1)*128] = A##j.y; \
                 ap[(4*j+2)*128] = A##j.z; ap[(4*j+3)*128] = A##j.w;
    R4(L3_ST)
#undef L3_ST
}

// ---------------- relu + pool4 over nodes
template<int LOGFB>
__global__ __launch_bounds__(256) void k_relu_pool(const float* __restrict__ acc, float* __restrict__ pool) {
    int i = blockIdx.x * 256 + threadIdx.x;
    int g = i >> LOGFB, rem = i & ((1 << LOGFB) - 1);
    float m = 0.f;
#pragma unroll
    for (int r = 0; r < 4; ++r) m = fmaxf(m, acc[((size_t)(4 * g + r) << LOGFB) + rem]);
    pool[i] = m;
}

// ---------------- FC1 partials: rowsplit 64, 8 b's per thread, 2048 blocks
// block = bg*128 + rs*2 + jh  (same-w blocks differ by 128 => same XCD for w reuse)
__global__ __launch_bounds__(256) void k_fc1_part(const float* __restrict__ t3, const float* __restrict__ w,
                           float* __restrict__ part) {
    int blk = blockIdx.x;
    int bg = blk >> 7;
    int rs = (blk >> 1) & 63;
    int j = ((blk & 1) << 8) + threadIdx.x;
    int b0 = bg << 3;
    float a0=0.f,a1=0.f,a2=0.f,a3=0.f,a4=0.f,a5=0.f,a6=0.f,a7=0.f;
    int r0 = rs << 8;
#pragma unroll 4
    for (int row = r0; row < r0 + 256; ++row) {
        float wv = w[((size_t)row << 9) + j];
        const float4* tp = (const float4*)(t3 + ((size_t)row << 7) + b0);
        float4 t0 = tp[0], t1 = tp[1];
        a0 = fmaf(t0.x, wv, a0);
        a1 = fmaf(t0.y, wv, a1);
        a2 = fmaf(t0.z, wv, a2);
        a3 = fmaf(t0.w, wv, a3);
        a4 = fmaf(t1.x, wv, a4);
        a5 = fmaf(t1.y, wv, a5);
        a6 = fmaf(t1.z, wv, a6);
        a7 = fmaf(t1.w, wv, a7);
    }
    float* pp = part + (((size_t)(rs << 7) + b0) << 9) + j;
    pp[0*512]=a0; pp[1*512]=a1; pp[2*512]=a2; pp[3*512]=a3;
    pp[4*512]=a4; pp[5*512]=a5; pp[6*512]=a6; pp[7*512]=a7;
}

__global__ __launch_bounds__(256) void k_fc1_red(const float* __restrict__ part, const float* __restrict__ bias,
                          float* __restrict__ h) {
    int i = blockIdx.x * 256 + threadIdx.x;   // i = b*512 + j
    float a = bias[i & 511];
#pragma unroll 8
    for (int rs = 0; rs < 64; ++rs) a += part[((size_t)rs << 16) + i];
    h[i] = a;
}

// ---------------- batchnorm stats over batch (biased var), store mean | inv_std
__global__ void k_bnstats(const float* __restrict__ h, float* __restrict__ mv) {
    __shared__ float s1[128], s2[128];
    int j = blockIdx.x, t = threadIdx.x;
    float v = h[(size_t)t * 512 + j];
    s1[t] = v; s2[t] = v * v;
    __syncthreads();
    for (int o = 64; o > 0; o >>= 1) {
        if (t < o) { s1[t] += s1[t + o]; s2[t] += s2[t + o]; }
        __syncthreads();
    }
    if (t == 0) {
        float m = s1[0] * (1.f / 128.f);
        float var = s2[0] * (1.f / 128.f) - m * m;
        mv[j] = m;
        mv[512 + j] = rsqrtf(var + 1e-5f);
    }
}

// ---------------- BN apply + relu + FC2 + log_softmax, one block per batch row
__global__ void k_head(const float* __restrict__ h, const float* __restrict__ mv,
                       const float* __restrict__ gamma, const float* __restrict__ beta,
                       const float* __restrict__ w2, const float* __restrict__ b2,
                       float* __restrict__ out) {
    __shared__ float hr[512];
    __shared__ float lg[16];
    int b = blockIdx.x, t = threadIdx.x;   // 64 threads
    for (int j = t; j < 512; j += 64) {
        float x = (h[(size_t)b * 512 + j] - mv[j]) * mv[512 + j] * gamma[j] + beta[j];
        hr[j] = fmaxf(x, 0.f);
    }
    __syncthreads();
    if (t < 10) {
        float a = b2[t];
        for (int j = 0; j < 512; ++j) a += hr[j] * w2[j * 10 + t];
        lg[t] = a;
    }
    __syncthreads();
    if (t == 0) {
        float mx = -1e30f;
        for (int q = 0; q < 10; ++q) mx = fmaxf(mx, lg[q]);
        float sum = 0.f;
        for (int q = 0; q < 10; ++q) sum += expf(lg[q] - mx);
        float ls = logf(sum) + mx;
        for (int q = 0; q < 10; ++q) out[b * 10 + q] = lg[q] - ls;
    }
}

extern "C" void kernel_launch(void* const* d_in, const int* in_sizes, int n_in,
                              void* d_out, int out_size, void* d_ws, size_t ws_size,
                              hipStream_t stream) {
    (void)in_sizes; (void)n_in; (void)out_size;
    const float* x      = (const float*)d_in[0];
    const int*   l0cols = (const int*)d_in[2];
    const float* l0vals = (const float*)d_in[3];
    const int*   l2cols = (const int*)d_in[5];
    const float* l2vals = (const float*)d_in[6];
    const int*   l4cols = (const int*)d_in[8];
    const float* l4vals = (const float*)d_in[9];
    const float* w1   = (const float*)d_in[10];
    const float* b1   = (const float*)d_in[11];
    const float* w2   = (const float*)d_in[12];
    const float* b2   = (const float*)d_in[13];
    const float* w3   = (const float*)d_in[14];
    const float* b3   = (const float*)d_in[15];
    const float* fc1w = (const float*)d_in[16];
    const float* fc1b = (const float*)d_in[17];
    const float* gam  = (const float*)d_in[18];
    const float* bet  = (const float*)d_in[19];
    const float* fc2w = (const float*)d_in[20];
    const float* fc2b = (const float*)d_in[21];
    float* out = (float*)d_out;

    const size_t S1 = 4096 * 128;    // layer-1 basis slot
    const size_t S2 = 1024 * 4096;   // layer-2 basis slot (= pool1 size)
    const size_t S3 = 256 * 8192;    // layer-3 basis slot (= pool2 / acc3 size)

    const size_t tailN = 128 * 512 + 1024;
    size_t need5 = (25 * S1 + 5 * S2 + tailN) * sizeof(float);
    int CK2 = (ws_size >= need5) ? 5 : 3;
    const int CK3 = 4;

    float* ws = (float*)d_ws;
    float* basis1 = ws;                              // 25 slots of S1
    float* basis2 = ws + 25 * S1;                    // ring CK2 slots; slot0 doubles as pool1
    float* acc2   = basis1;                          // alias: basis1 dead after proj1
    float* basis3 = basis2;                          // ring CK3 slots; slot0 doubles as pool2
    float* acc3   = basis2 + (size_t)CK3 * S3;       // beyond basis3 ring
    float* part   = basis1;                          // alias: 64*128*512 = 4.2M <= 13.1M, acc2 dead
    float* tail   = basis2 + (size_t)CK2 * S2;
    float* h      = tail;                            // 65536
    float* mv     = h + 65536;                       // 1024

    // ---------------- Layer 1: V=4096, C=128, full basis ----------------
    k_transpose_x<<<2048, 256, 0, stream>>>(x, basis1);
    for (int k = 1; k < 25; ++k) {
        const float* cur  = basis1 + (size_t)(k - 1) * S1;
        const float* prev = (k >= 2) ? basis1 + (size_t)(k - 2) * S1 : cur;
        float* next = basis1 + (size_t)k * S1;
        k_spmm1<<<1024, 256, 0, stream>>>(l0cols, l0vals, (const float2*)cur,
                                          (const float2*)prev, (float2*)next, k >= 2 ? 1 : 0);
    }
    k_proj1_pool<<<dim3(512, 2), 256, 0, stream>>>(basis1, w1, b1, basis2 /*pool1 = slot0*/);

    // ---------------- Layer 2: V=1024, C=4096, ring CK2 ----------------
    {
        int cs = 0;
        for (int k = 0; k < 25; ++k) {
            if (k >= 1) {
                const float* cur  = basis2 + (size_t)((k - 1) % CK2) * S2;
                const float* prev = basis2 + (size_t)((k >= 2 ? k - 2 : 0) % CK2) * S2;
                float* next = basis2 + (size_t)(k % CK2) * S2;
                k_spmm4<10><<<4096, 256, 0, stream>>>(l2cols, l2vals, (const float4*)cur,
                                                      (const float4*)prev, (float4*)next, k >= 2 ? 1 : 0);
            }
            if (k - cs + 1 == CK2 || k == 24) {
                k_proj_l2<<<512, 256, 0, stream>>>(basis2, S2, w2, acc2, cs, k - cs + 1,
                                                   cs == 0 ? 1 : 0, b2);
                cs = k + 1;
            }
        }
    }
    k_relu_pool<13><<<8192, 256, 0, stream>>>(acc2, basis3 /*pool2 = slot0*/);

    // ---------------- Layer 3: V=256, C=8192, ring CK3=4 ----------------
    {
        int cs = 0;
        for (int k = 0; k < 25; ++k) {
            if (k >= 1) {
                const float* cur  = basis3 + (size_t)((k - 1) % CK3) * S3;
                const float* prev = basis3 + (size_t)((k >= 2 ? k - 2 : 0) % CK3) * S3;
                float* next = basis3 + (size_t)(k % CK3) * S3;
                k_spmm4<11><<<2048, 256, 0, stream>>>(l4cols, l4vals, (const float4*)cur,
                                                      (const float4*)prev, (float4*)next, k >= 2 ? 1 : 0);
            }
            if (k - cs + 1 == CK3 || k == 24) {
                int kcnt = k - cs + 1;
                k_proj_l3<<<dim3(128, 4), 256, 0, stream>>>(basis3, S3, w3, acc3, cs, kcnt,
                                                            cs == 0 ? 1 : 0, b3,
                                                            (cs + kcnt == 25) ? 1 : 0);
                cs = k + 1;
            }
        }
    }

    // ---------------- FC1 + BN + FC2 + log_softmax ----------------
    k_fc1_part<<<2048, 256, 0, stream>>>(acc3, fc1w, part);
    k_fc1_red<<<256, 256, 0, stream>>>(part, fc1b, h);
    k_bnstats<<<512, 128, 0, stream>>>(h, mv);
    k_head<<<128, 64, 0, stream>>>(h, mv, gam, bet, fc2w, fc2b, out);
}

// Round 5
// 1018.385 us; speedup vs baseline: 2.5891x; 1.1850x over previous
//
#include <hip/hip_runtime.h>

#define B_ 128
#define K_ 25
#define DEG_ 16

#define R4(X) X(0) X(1) X(2) X(3)
#define R8(X) X(0) X(1) X(2) X(3) X(4) X(5) X(6) X(7)
#define R16(X) X(0) X(1) X(2) X(3) X(4) X(5) X(6) X(7) X(8) X(9) X(10) X(11) X(12) X(13) X(14) X(15)

__device__ __forceinline__ float4 f4ma(float t, float4 w, float4 a) {
    a.x = fmaf(t, w.x, a.x); a.y = fmaf(t, w.y, a.y);
    a.z = fmaf(t, w.z, a.z); a.w = fmaf(t, w.w, a.w);
    return a;
}
__device__ __forceinline__ float4 f4max(float4 a, float4 b) {
    return make_float4(fmaxf(a.x, b.x), fmaxf(a.y, b.y), fmaxf(a.z, b.z), fmaxf(a.w, b.w));
}

// ---------------- transpose x: (B=128, N=4096) -> x0 (4096, 128)
__global__ __launch_bounds__(256) void k_transpose_x(const float* __restrict__ x, float* __restrict__ x0) {
    int i = blockIdx.x * 256 + threadIdx.x;   // i = v*128 + b
    int v = i >> 7, b = i & 127;
    x0[i] = x[(b << 12) + v];
}

// ---------------- layer-1 SpMM: one wave per row v, lane = float2 column (C=128 -> 64 f2)
__global__ __launch_bounds__(256) void k_spmm1(const int* __restrict__ cols, const float* __restrict__ vals,
        const float2* __restrict__ cur, const float2* __restrict__ prev,
        float2* __restrict__ next, int two) {
    int t = blockIdx.x * 256 + threadIdx.x;
    int v = __builtin_amdgcn_readfirstlane(t >> 6);
    int lane = threadIdx.x & 63;
    int base = v * DEG_;
    float2 s = make_float2(0.f, 0.f);
#pragma unroll
    for (int d = 0; d < DEG_; ++d) {
        float wv = vals[base + d];
        float2 xx = cur[((size_t)cols[base + d] << 6) + lane];
        s.x = fmaf(wv, xx.x, s.x); s.y = fmaf(wv, xx.y, s.y);
    }
    size_t idx = ((size_t)v << 6) + lane;
    if (two) {
        float2 p = prev[idx];
        s.x = 2.f * s.x - p.x; s.y = 2.f * s.y - p.y;
    }
    next[idx] = s;
}

// ---------------- SpMM (layers 2/3, float4 columns, XCD slab swizzle, wave-uniform row)
template<int LOGC4>
__global__ __launch_bounds__(256) void k_spmm4(const int* __restrict__ cols, const float* __restrict__ vals,
                        const float4* __restrict__ cur, const float4* __restrict__ prev,
                        float4* __restrict__ next, int two) {
    constexpr int LOGW4 = LOGC4 - 3;
    int xcd = blockIdx.x & 7, q = blockIdx.x >> 3;
    int tid = q * 256 + threadIdx.x;
    int v = __builtin_amdgcn_readfirstlane(tid >> LOGW4);
    int c4 = (xcd << LOGW4) + (tid & ((1 << LOGW4) - 1));
    int base = v * DEG_;
    float4 s = make_float4(0.f, 0.f, 0.f, 0.f);
#pragma unroll
    for (int d = 0; d < DEG_; ++d) {
        float w = vals[base + d];
        float4 xx = cur[((size_t)cols[base + d] << LOGC4) + c4];
        s = f4ma(w, xx, s);
    }
    size_t idx = ((size_t)v << LOGC4) + c4;
    if (two) {
        float4 p = prev[idx];
        s.x = 2.f * s.x - p.x; s.y = 2.f * s.y - p.y;
        s.z = 2.f * s.z - p.z; s.w = 2.f * s.w - p.w;
    }
    next[idx] = s;
}

// ---------------- layer 1 projection (Fin=1, Fout=32) + bias + relu + pool4
__global__ __launch_bounds__(256) void k_proj1_pool(const float* __restrict__ basis,
        const float* __restrict__ W1, const float* __restrict__ b1, float* __restrict__ pool1) {
    int half = blockIdx.y;
    int i = blockIdx.x * 256 + threadIdx.x;   // i = g*128 + b
    int g = i >> 7, b = i & 127;
    const float* wbase = W1 + half * 16;
#define P1_DM(j) float4 M##j = make_float4(-1e30f, -1e30f, -1e30f, -1e30f);
    R4(P1_DM)
#undef P1_DM
    for (int r = 0; r < 4; ++r) {
        const float* bp = basis + (((size_t)(4 * g + r) << 7) + b);
#define P1_DC(j) float4 C##j = make_float4(0.f, 0.f, 0.f, 0.f);
        R4(P1_DC)
#undef P1_DC
#pragma unroll 5
        for (int k = 0; k < K_; ++k) {
            float tv = bp[(size_t)k * 524288];
            const float4* w = (const float4*)(wbase + k * 32);
#define P1_FM(j) C##j = f4ma(tv, w[j], C##j);
            R4(P1_FM)
#undef P1_FM
        }
#define P1_MX(j) M##j = f4max(M##j, C##j);
        R4(P1_MX)
#undef P1_MX
    }
    float* op = pool1 + ((size_t)g << 12) + ((size_t)half << 11) + b;
    const float* bb = b1 + half * 16;
#define P1_ST(j) \
    op[(4*j+0)*128] = fmaxf(M##j.x + bb[4*j+0], 0.f); \
    op[(4*j+1)*128] = fmaxf(M##j.y + bb[4*j+1], 0.f); \
    op[(4*j+2)*128] = fmaxf(M##j.z + bb[4*j+2], 0.f); \
    op[(4*j+3)*128] = fmaxf(M##j.w + bb[4*j+3], 0.f);
    R4(P1_ST)
#undef P1_ST
}

// ---------------- layer-2 chunk projection: Fin=32, Fout=64 in 2 slices of 32 (grid.y)
// W via wave-uniform s_load; acc[v][fo][b] (+)= sum basis[kk][v][fi][b] * W[fi*25+k0+kk][fo]
__global__ __launch_bounds__(256) void k_proj_l2(const float* __restrict__ basis, size_t slotStride,
        const float* __restrict__ W, float* __restrict__ acc, int k0, int kcnt, int init,
        const float* __restrict__ bias) {
    int fo0 = blockIdx.y << 5;
    int i = blockIdx.x * 256 + threadIdx.x;   // i = v*128 + b, v in [0,1024)
    int v = i >> 7, b = i & 127;
    float* ap = acc + ((size_t)v << 13) + ((size_t)fo0 << 7) + b;
    const float* bb = bias + fo0;
#define L2_DA(j) float4 A##j;
    R8(L2_DA)
#undef L2_DA
    if (init) {
#define L2_IN(j) A##j = make_float4(bb[4*j+0], bb[4*j+1], bb[4*j+2], bb[4*j+3]);
        R8(L2_IN)
#undef L2_IN
    } else {
#define L2_LD(j) A##j = make_float4(ap[(4*j+0)*128], ap[(4*j+1)*128], ap[(4*j+2)*128], ap[(4*j+3)*128]);
        R8(L2_LD)
#undef L2_LD
    }
    const float* bp0 = basis + ((size_t)v << 12) + b;
    for (int kk = 0; kk < kcnt; ++kk) {
        const float* bp = bp0 + (size_t)kk * slotStride;
        const float* wk = W + (size_t)(k0 + kk) * 64 + fo0;
#pragma unroll 4
        for (int fi = 0; fi < 32; ++fi) {
            float tv = bp[fi << 7];
            const float4* w = (const float4*)(wk + (size_t)fi * (K_ * 64));
#define L2_FM(j) A##j = f4ma(tv, w[j], A##j);
            R8(L2_FM)
#undef L2_FM
        }
    }
#define L2_ST(j) ap[(4*j+0)*128] = A##j.x; ap[(4*j+1)*128] = A##j.y; \
                 ap[(4*j+2)*128] = A##j.z; ap[(4*j+3)*128] = A##j.w;
    R8(L2_ST)
#undef L2_ST
}

// ---------------- layer-3 chunk projection: Fin=64, Fout=64 in 4 slices of 16 (grid.y)
__global__ __launch_bounds__(256) void k_proj_l3(const float* __restrict__ basis, size_t slotStride,
        const float* __restrict__ W, float* __restrict__ acc, int k0, int kcnt, int init,
        const float* __restrict__ bias, int finalrelu) {
    int fo0 = blockIdx.y << 4;
    int i = blockIdx.x * 256 + threadIdx.x;   // i = v*128 + b, v in [0,256)
    int v = i >> 7, b = i & 127;
    float* ap = acc + ((size_t)v << 13) + ((size_t)fo0 << 7) + b;
    const float* bb = bias + fo0;
#define L3_DA(j) float4 A##j;
    R4(L3_DA)
#undef L3_DA
    if (init) {
#define L3_IN(j) A##j = make_float4(bb[4*j+0], bb[4*j+1], bb[4*j+2], bb[4*j+3]);
        R4(L3_IN)
#undef L3_IN
    } else {
#define L3_LD(j) A##j = make_float4(ap[(4*j+0)*128], ap[(4*j+1)*128], ap[(4*j+2)*128], ap[(4*j+3)*128]);
        R4(L3_LD)
#undef L3_LD
    }
    const float* bp0 = basis + ((size_t)v << 13) + b;
    for (int kk = 0; kk < kcnt; ++kk) {
        const float* bp = bp0 + (size_t)kk * slotStride;
        const float* wk = W + (size_t)(k0 + kk) * 64 + fo0;
#pragma unroll 4
        for (int fi = 0; fi < 64; ++fi) {
            float tv = bp[fi << 7];
            const float4* w = (const float4*)(wk + (size_t)fi * (K_ * 64));
#define L3_FM(j) A##j = f4ma(tv, w[j], A##j);
            R4(L3_FM)
#undef L3_FM
        }
    }
    if (finalrelu) {
        float4 z = make_float4(0.f, 0.f, 0.f, 0.f);
#define L3_RL(j) A##j = f4max(A##j, z);
        R4(L3_RL)
#undef L3_RL
    }
#define L3_ST(j) ap[(4*j+0)*128] = A##j.x; ap[(4*j+1)*128] = A##j.y; \
                 ap[(4*j+2)*128] = A##j.z; ap[(4*j+3)*128] = A##j.w;
    R4(L3_ST)
#undef L3_ST
}

// ---------------- relu + pool4 over nodes
template<int LOGFB>
__global__ __launch_bounds__(256) void k_relu_pool(const float* __restrict__ acc, float* __restrict__ pool) {
    int i = blockIdx.x * 256 + threadIdx.x;
    int g = i >> LOGFB, rem = i & ((1 << LOGFB) - 1);
    float m = 0.f;
#pragma unroll
    for (int r = 0; r < 4; ++r) m = fmaxf(m, acc[((size_t)(4 * g + r) << LOGFB) + rem]);
    pool[i] = m;
}

// ---------------- FC1 partials: rowsplit 64, 8 b's per thread, 2048 blocks
__global__ __launch_bounds__(256) void k_fc1_part(const float* __restrict__ t3, const float* __restrict__ w,
                           float* __restrict__ part) {
    int blk = blockIdx.x;
    int bg = blk >> 7;
    int rs = (blk >> 1) & 63;
    int j = ((blk & 1) << 8) + threadIdx.x;
    int b0 = bg << 3;
    float a0=0.f,a1=0.f,a2=0.f,a3=0.f,a4=0.f,a5=0.f,a6=0.f,a7=0.f;
    int r0 = rs << 8;
#pragma unroll 4
    for (int row = r0; row < r0 + 256; ++row) {
        float wv = w[((size_t)row << 9) + j];
        const float4* tp = (const float4*)(t3 + ((size_t)row << 7) + b0);
        float4 t0 = tp[0], t1 = tp[1];
        a0 = fmaf(t0.x, wv, a0);
        a1 = fmaf(t0.y, wv, a1);
        a2 = fmaf(t0.z, wv, a2);
        a3 = fmaf(t0.w, wv, a3);
        a4 = fmaf(t1.x, wv, a4);
        a5 = fmaf(t1.y, wv, a5);
        a6 = fmaf(t1.z, wv, a6);
        a7 = fmaf(t1.w, wv, a7);
    }
    float* pp = part + (((size_t)(rs << 7) + b0) << 9) + j;
    pp[0*512]=a0; pp[1*512]=a1; pp[2*512]=a2; pp[3*512]=a3;
    pp[4*512]=a4; pp[5*512]=a5; pp[6*512]=a6; pp[7*512]=a7;
}

__global__ __launch_bounds__(256) void k_fc1_red(const float* __restrict__ part, const float* __restrict__ bias,
                          float* __restrict__ h) {
    int i = blockIdx.x * 256 + threadIdx.x;   // i = b*512 + j
    float a = bias[i & 511];
#pragma unroll 8
    for (int rs = 0; rs < 64; ++rs) a += part[((size_t)rs << 16) + i];
    h[i] = a;
}

// ---------------- batchnorm stats over batch (biased var), store mean | inv_std
__global__ void k_bnstats(const float* __restrict__ h, float* __restrict__ mv) {
    __shared__ float s1[128], s2[128];
    int j = blockIdx.x, t = threadIdx.x;
    float v = h[(size_t)t * 512 + j];
    s1[t] = v; s2[t] = v * v;
    __syncthreads();
    for (int o = 64; o > 0; o >>= 1) {
        if (t < o) { s1[t] += s1[t + o]; s2[t] += s2[t + o]; }
        __syncthreads();
    }
    if (t == 0) {
        float m = s1[0] * (1.f / 128.f);
        float var = s2[0] * (1.f / 128.f) - m * m;
        mv[j] = m;
        mv[512 + j] = rsqrtf(var + 1e-5f);
    }
}

// ---------------- BN apply + relu + FC2 + log_softmax, one block per batch row
__global__ void k_head(const float* __restrict__ h, const float* __restrict__ mv,
                       const float* __restrict__ gamma, const float* __restrict__ beta,
                       const float* __restrict__ w2, const float* __restrict__ b2,
                       float* __restrict__ out) {
    __shared__ float hr[512];
    __shared__ float lg[16];
    int b = blockIdx.x, t = threadIdx.x;   // 64 threads
    for (int j = t; j < 512; j += 64) {
        float x = (h[(size_t)b * 512 + j] - mv[j]) * mv[512 + j] * gamma[j] + beta[j];
        hr[j] = fmaxf(x, 0.f);
    }
    __syncthreads();
    if (t < 10) {
        float a = b2[t];
        for (int j = 0; j < 512; ++j) a += hr[j] * w2[j * 10 + t];
        lg[t] = a;
    }
    __syncthreads();
    if (t == 0) {
        float mx = -1e30f;
        for (int q = 0; q < 10; ++q) mx = fmaxf(mx, lg[q]);
        float sum = 0.f;
        for (int q = 0; q < 10; ++q) sum += expf(lg[q] - mx);
        float ls = logf(sum) + mx;
        for (int q = 0; q < 10; ++q) out[b * 10 + q] = lg[q] - ls;
    }
}

extern "C" void kernel_launch(void* const* d_in, const int* in_sizes, int n_in,
                              void* d_out, int out_size, void* d_ws, size_t ws_size,
                              hipStream_t stream) {
    (void)in_sizes; (void)n_in; (void)out_size;
    const float* x      = (const float*)d_in[0];
    const int*   l0cols = (const int*)d_in[2];
    const float* l0vals = (const float*)d_in[3];
    const int*   l2cols = (const int*)d_in[5];
    const float* l2vals = (const float*)d_in[6];
    const int*   l4cols = (const int*)d_in[8];
    const float* l4vals = (const float*)d_in[9];
    const float* w1   = (const float*)d_in[10];
    const float* b1   = (const float*)d_in[11];
    const float* w2   = (const float*)d_in[12];
    const float* b2   = (const float*)d_in[13];
    const float* w3   = (const float*)d_in[14];
    const float* b3   = (const float*)d_in[15];
    const float* fc1w = (const float*)d_in[16];
    const float* fc1b = (const float*)d_in[17];
    const float* gam  = (const float*)d_in[18];
    const float* bet  = (const float*)d_in[19];
    const float* fc2w = (const float*)d_in[20];
    const float* fc2b = (const float*)d_in[21];
    float* out = (float*)d_out;

    const size_t S1 = 4096 * 128;    // layer-1 basis slot
    const size_t S2 = 1024 * 4096;   // layer-2 basis slot (= pool1 size)
    const size_t S3 = 256 * 8192;    // layer-3 basis slot (= pool2 / acc3 size)

    // chunk-ring tiers by workspace size:
    //   CK2=9 -> 3 proj_l2 calls; CK2=5 -> 5; CK2=3 -> 9.  CK3 sized so CK3*S3+S3 <= CK2*S2.
    const size_t tailN = 128 * 512 + 1024;
    size_t need9 = (25 * S1 + 9 * S2 + tailN) * sizeof(float);
    size_t need5 = (25 * S1 + 5 * S2 + tailN) * sizeof(float);
    int CK2 = (ws_size >= need9) ? 9 : (ws_size >= need5) ? 5 : 3;
    int CK3 = (CK2 == 3) ? 5 : 9;

    float* ws = (float*)d_ws;
    float* basis1 = ws;                              // 25 slots of S1
    float* basis2 = ws + 25 * S1;                    // ring CK2 slots; slot0 doubles as pool1
    float* acc2   = basis1;                          // alias: basis1 dead after proj1
    float* basis3 = basis2;                          // ring CK3 slots; slot0 doubles as pool2
    float* acc3   = basis2 + (size_t)CK3 * S3;       // CK3*S3+S3 <= CK2*S2 in every tier
    float* part   = basis1;                          // alias: 4.2M <= 13.1M, acc2 dead
    float* tail   = basis2 + (size_t)CK2 * S2;
    float* h      = tail;                            // 65536
    float* mv     = h + 65536;                       // 1024

    // ---------------- Layer 1: V=4096, C=128, full basis ----------------
    k_transpose_x<<<2048, 256, 0, stream>>>(x, basis1);
    for (int k = 1; k < 25; ++k) {
        const float* cur  = basis1 + (size_t)(k - 1) * S1;
        const float* prev = (k >= 2) ? basis1 + (size_t)(k - 2) * S1 : cur;
        float* next = basis1 + (size_t)k * S1;
        k_spmm1<<<1024, 256, 0, stream>>>(l0cols, l0vals, (const float2*)cur,
                                          (const float2*)prev, (float2*)next, k >= 2 ? 1 : 0);
    }
    k_proj1_pool<<<dim3(512, 2), 256, 0, stream>>>(basis1, w1, b1, basis2 /*pool1 = slot0*/);

    // ---------------- Layer 2: V=1024, C=4096, ring CK2 ----------------
    {
        int cs = 0;
        for (int k = 0; k < 25; ++k) {
            if (k >= 1) {
                const float* cur  = basis2 + (size_t)((k - 1) % CK2) * S2;
                const float* prev = basis2 + (size_t)((k >= 2 ? k - 2 : 0) % CK2) * S2;
                float* next = basis2 + (size_t)(k % CK2) * S2;
                k_spmm4<10><<<4096, 256, 0, stream>>>(l2cols, l2vals, (const float4*)cur,
                                                      (const float4*)prev, (float4*)next, k >= 2 ? 1 : 0);
            }
            if (k - cs + 1 == CK2 || k == 24) {
                k_proj_l2<<<dim3(512, 2), 256, 0, stream>>>(basis2, S2, w2, acc2, cs, k - cs + 1,
                                                            cs == 0 ? 1 : 0, b2);
                cs = k + 1;
            }
        }
    }
    k_relu_pool<13><<<8192, 256, 0, stream>>>(acc2, basis3 /*pool2 = slot0*/);

    // ---------------- Layer 3: V=256, C=8192, ring CK3 ----------------
    {
        int cs = 0;
        for (int k = 0; k < 25; ++k) {
            if (k >= 1) {
                const float* cur  = basis3 + (size_t)((k - 1) % CK3) * S3;
                const float* prev = basis3 + (size_t)((k >= 2 ? k - 2 : 0) % CK3) * S3;
                float* next = basis3 + (size_t)(k % CK3) * S3;
                k_spmm4<11><<<2048, 256, 0, stream>>>(l4cols, l4vals, (const float4*)cur,
                                                      (const float4*)prev, (float4*)next, k >= 2 ? 1 : 0);
            }
            if (k - cs + 1 == CK3 || k == 24) {
                int kcnt = k - cs + 1;
                k_proj_l3<<<dim3(128, 4), 256, 0, stream>>>(basis3, S3, w3, acc3, cs, kcnt,
                                                            cs == 0 ? 1 : 0, b3,
                                                            (cs + kcnt == 25) ? 1 : 0);
                cs = k + 1;
            }
        }
    }

    // ---------------- FC1 + BN + FC2 + log_softmax ----------------
    k_fc1_part<<<2048, 256, 0, stream>>>(acc3, fc1w, part);
    k_fc1_red<<<256, 256, 0, stream>>>(part, fc1b, h);
    k_bnstats<<<512, 128, 0, stream>>>(h, mv);
    k_head<<<128, 64, 0, stream>>>(h, mv, gam, bet, fc2w, fc2b, out);
}

// Round 6
// 1017.317 us; speedup vs baseline: 2.5918x; 1.0010x over previous
//
#include <hip/hip_runtime.h>

#define B_ 128
#define K_ 25
#define DEG_ 16

#define R4(X) X(0) X(1) X(2) X(3)
#define R8(X) X(0) X(1) X(2) X(3) X(4) X(5) X(6) X(7)
#define R16(X) X(0) X(1) X(2) X(3) X(4) X(5) X(6) X(7) X(8) X(9) X(10) X(11) X(12) X(13) X(14) X(15)

__device__ __forceinline__ float4 f4ma(float t, float4 w, float4 a) {
    a.x = fmaf(t, w.x, a.x); a.y = fmaf(t, w.y, a.y);
    a.z = fmaf(t, w.z, a.z); a.w = fmaf(t, w.w, a.w);
    return a;
}
__device__ __forceinline__ float4 f4max(float4 a, float4 b) {
    return make_float4(fmaxf(a.x, b.x), fmaxf(a.y, b.y), fmaxf(a.z, b.z), fmaxf(a.w, b.w));
}
// bf16 pack/unpack (RTNE)
__device__ __forceinline__ unsigned f2bfu(float f) {
    unsigned u = __float_as_uint(f);
    return (u + 0x7FFFu + ((u >> 16) & 1u)) >> 16;
}
__device__ __forceinline__ unsigned packbf(float e, float o) { return f2bfu(e) | (f2bfu(o) << 16); }
__device__ __forceinline__ float bflo(unsigned u) { return __uint_as_float(u << 16); }
__device__ __forceinline__ float bfhi(unsigned u) { return __uint_as_float(u & 0xFFFF0000u); }

// ---------------- transpose x: (B=128, N=4096) -> x0 (4096, 128)
__global__ __launch_bounds__(256) void k_transpose_x(const float* __restrict__ x, float* __restrict__ x0) {
    int i = blockIdx.x * 256 + threadIdx.x;   // i = v*128 + b
    int v = i >> 7, b = i & 127;
    x0[i] = x[(b << 12) + v];
}

// ---------------- layer-1 SpMM: one wave per row v, lane = float2 column (C=128 -> 64 f2)
__global__ __launch_bounds__(256) void k_spmm1(const int* __restrict__ cols, const float* __restrict__ vals,
        const float2* __restrict__ cur, const float2* __restrict__ prev,
        float2* __restrict__ next, int two) {
    int t = blockIdx.x * 256 + threadIdx.x;
    int v = __builtin_amdgcn_readfirstlane(t >> 6);
    int lane = threadIdx.x & 63;
    int base = v * DEG_;
    float2 s = make_float2(0.f, 0.f);
#pragma unroll
    for (int d = 0; d < DEG_; ++d) {
        float wv = vals[base + d];
        float2 xx = cur[((size_t)cols[base + d] << 6) + lane];
        s.x = fmaf(wv, xx.x, s.x); s.y = fmaf(wv, xx.y, s.y);
    }
    size_t idx = ((size_t)v << 6) + lane;
    if (two) {
        float2 p = prev[idx];
        s.x = 2.f * s.x - p.x; s.y = 2.f * s.y - p.y;
    }
    next[idx] = s;
}

// ---------------- SpMM (layers 2/3) + packed-bf16 mirror write
// XCD slab swizzle, wave-uniform row. A wave's lanes 0-31 carry fi (even), 32-63 carry fi+1
// for the same 128 b's -> shfl_down(32) pairs them; lanes<32 store uint4 of (fi,fi+1) bf16
// pairs into mirror layout [v][fi2][b] (dwords).
template<int LOGC4>
__global__ __launch_bounds__(256) void k_spmm4(const int* __restrict__ cols, const float* __restrict__ vals,
                        const float4* __restrict__ cur, const float4* __restrict__ prev,
                        float4* __restrict__ next, unsigned* __restrict__ mir, int two) {
    constexpr int LOGW4 = LOGC4 - 3;
    int xcd = blockIdx.x & 7, q = blockIdx.x >> 3;
    int tid = q * 256 + threadIdx.x;
    int v = __builtin_amdgcn_readfirstlane(tid >> LOGW4);
    int c4 = (xcd << LOGW4) + (tid & ((1 << LOGW4) - 1));
    int base = v * DEG_;
    float4 s = make_float4(0.f, 0.f, 0.f, 0.f);
#pragma unroll
    for (int d = 0; d < DEG_; ++d) {
        float w = vals[base + d];
        float4 xx = cur[((size_t)cols[base + d] << LOGC4) + c4];
        s = f4ma(w, xx, s);
    }
    size_t idx = ((size_t)v << LOGC4) + c4;
    if (two) {
        float4 p = prev[idx];
        s.x = 2.f * s.x - p.x; s.y = 2.f * s.y - p.y;
        s.z = 2.f * s.z - p.z; s.w = 2.f * s.w - p.w;
    }
    next[idx] = s;
    float tx = __shfl_down(s.x, 32), ty = __shfl_down(s.y, 32),
          tz = __shfl_down(s.z, 32), tw = __shfl_down(s.w, 32);
    if ((threadIdx.x & 63) < 32) {
        int c = c4 << 2;
        int fi2 = c >> 8, b0 = c & 127;
        uint4 m = make_uint4(packbf(s.x, tx), packbf(s.y, ty), packbf(s.z, tz), packbf(s.w, tw));
        *(uint4*)(mir + ((size_t)v << (LOGC4 + 1)) + ((size_t)fi2 << 7) + b0) = m;
    }
}

// ---------------- layer 1 projection (Fin=1, Fout=32) + bias + relu + pool4 (+ bf16 mirror of pool1)
__global__ __launch_bounds__(256) void k_proj1_pool(const float* __restrict__ basis,
        const float* __restrict__ W1, const float* __restrict__ b1, float* __restrict__ pool1,
        unsigned* __restrict__ mir) {
    int half = blockIdx.y;
    int i = blockIdx.x * 256 + threadIdx.x;   // i = g*128 + b
    int g = i >> 7, b = i & 127;
    const float* wbase = W1 + half * 16;
#define P1_DM(j) float4 M##j = make_float4(-1e30f, -1e30f, -1e30f, -1e30f);
    R4(P1_DM)
#undef P1_DM
    for (int r = 0; r < 4; ++r) {
        const float* bp = basis + (((size_t)(4 * g + r) << 7) + b);
#define P1_DC(j) float4 C##j = make_float4(0.f, 0.f, 0.f, 0.f);
        R4(P1_DC)
#undef P1_DC
#pragma unroll 5
        for (int k = 0; k < K_; ++k) {
            float tv = bp[(size_t)k * 524288];
            const float4* w = (const float4*)(wbase + k * 32);
#define P1_FM(j) C##j = f4ma(tv, w[j], C##j);
            R4(P1_FM)
#undef P1_FM
        }
#define P1_MX(j) M##j = f4max(M##j, C##j);
        R4(P1_MX)
#undef P1_MX
    }
    float* op = pool1 + ((size_t)g << 12) + ((size_t)half << 11) + b;
    unsigned* mp = mir + ((size_t)g << 11) + ((size_t)half << 10) + b;
    const float* bb = b1 + half * 16;
#define P1_ST(j) { \
    float e0 = fmaxf(M##j.x + bb[4*j+0], 0.f); \
    float o0 = fmaxf(M##j.y + bb[4*j+1], 0.f); \
    float e1 = fmaxf(M##j.z + bb[4*j+2], 0.f); \
    float o1 = fmaxf(M##j.w + bb[4*j+3], 0.f); \
    op[(4*j+0)*128] = e0; op[(4*j+1)*128] = o0; \
    op[(4*j+2)*128] = e1; op[(4*j+3)*128] = o1; \
    mp[(2*j+0)*128] = packbf(e0, o0); \
    mp[(2*j+1)*128] = packbf(e1, o1); }
    R4(P1_ST)
#undef P1_ST
}

// ---------------- layer-2 chunk projection from bf16 mirror: Fin=32, Fout=64 in 4 slices of 16
__global__ __launch_bounds__(256) void k_proj_l2(const unsigned* __restrict__ mir, size_t slotH,
        const float* __restrict__ W, float* __restrict__ acc, int k0, int kcnt, int init,
        const float* __restrict__ bias) {
    int fo0 = blockIdx.y << 4;
    int i = blockIdx.x * 256 + threadIdx.x;   // i = v*128 + b, v in [0,1024)
    int v = i >> 7, b = i & 127;
    float* ap = acc + ((size_t)v << 13) + ((size_t)fo0 << 7) + b;
    const float* bb = bias + fo0;
    float4 A0, A1, A2, A3;
    if (init) {
        A0 = make_float4(bb[0], bb[1], bb[2], bb[3]);
        A1 = make_float4(bb[4], bb[5], bb[6], bb[7]);
        A2 = make_float4(bb[8], bb[9], bb[10], bb[11]);
        A3 = make_float4(bb[12], bb[13], bb[14], bb[15]);
    } else {
        A0 = make_float4(ap[0*128], ap[1*128], ap[2*128], ap[3*128]);
        A1 = make_float4(ap[4*128], ap[5*128], ap[6*128], ap[7*128]);
        A2 = make_float4(ap[8*128], ap[9*128], ap[10*128], ap[11*128]);
        A3 = make_float4(ap[12*128], ap[13*128], ap[14*128], ap[15*128]);
    }
    const unsigned* mp0 = mir + ((size_t)v << 11) + b;
    for (int kk = 0; kk < kcnt; ++kk) {
        const unsigned* mp = mp0 + (size_t)kk * slotH;
        const float* wk = W + (size_t)(k0 + kk) * 64 + fo0;
#pragma unroll 8
        for (int fi2 = 0; fi2 < 16; ++fi2) {
            unsigned u = mp[fi2 << 7];
            float fe = bflo(u), fod = bfhi(u);
            const float4* we = (const float4*)(wk + (size_t)(2 * fi2) * (K_ * 64));
            const float4* wo = (const float4*)(wk + (size_t)(2 * fi2 + 1) * (K_ * 64));
            A0 = f4ma(fe, we[0], A0); A1 = f4ma(fe, we[1], A1);
            A2 = f4ma(fe, we[2], A2); A3 = f4ma(fe, we[3], A3);
            A0 = f4ma(fod, wo[0], A0); A1 = f4ma(fod, wo[1], A1);
            A2 = f4ma(fod, wo[2], A2); A3 = f4ma(fod, wo[3], A3);
        }
    }
    ap[0*128] = A0.x; ap[1*128] = A0.y; ap[2*128] = A0.z; ap[3*128] = A0.w;
    ap[4*128] = A1.x; ap[5*128] = A1.y; ap[6*128] = A1.z; ap[7*128] = A1.w;
    ap[8*128] = A2.x; ap[9*128] = A2.y; ap[10*128] = A2.z; ap[11*128] = A2.w;
    ap[12*128] = A3.x; ap[13*128] = A3.y; ap[14*128] = A3.z; ap[15*128] = A3.w;
}

// ---------------- layer-3 chunk projection from bf16 mirror: Fin=64, Fout=64 in 8 slices of 8
__global__ __launch_bounds__(256) void k_proj_l3(const unsigned* __restrict__ mir, size_t slotH,
        const float* __restrict__ W, float* __restrict__ acc, int k0, int kcnt, int init,
        const float* __restrict__ bias, int finalrelu) {
    int fo0 = blockIdx.y << 3;
    int i = blockIdx.x * 256 + threadIdx.x;   // i = v*128 + b, v in [0,256)
    int v = i >> 7, b = i & 127;
    float* ap = acc + ((size_t)v << 13) + ((size_t)fo0 << 7) + b;
    const float* bb = bias + fo0;
    float4 A0, A1;
    if (init) {
        A0 = make_float4(bb[0], bb[1], bb[2], bb[3]);
        A1 = make_float4(bb[4], bb[5], bb[6], bb[7]);
    } else {
        A0 = make_float4(ap[0*128], ap[1*128], ap[2*128], ap[3*128]);
        A1 = make_float4(ap[4*128], ap[5*128], ap[6*128], ap[7*128]);
    }
    const unsigned* mp0 = mir + ((size_t)v << 12) + b;
    for (int kk = 0; kk < kcnt; ++kk) {
        const unsigned* mp = mp0 + (size_t)kk * slotH;
        const float* wk = W + (size_t)(k0 + kk) * 64 + fo0;
#pragma unroll 8
        for (int fi2 = 0; fi2 < 32; ++fi2) {
            unsigned u = mp[fi2 << 7];
            float fe = bflo(u), fod = bfhi(u);
            const float4* we = (const float4*)(wk + (size_t)(2 * fi2) * (K_ * 64));
            const float4* wo = (const float4*)(wk + (size_t)(2 * fi2 + 1) * (K_ * 64));
            A0 = f4ma(fe, we[0], A0); A1 = f4ma(fe, we[1], A1);
            A0 = f4ma(fod, wo[0], A0); A1 = f4ma(fod, wo[1], A1);
        }
    }
    if (finalrelu) {
        float4 z = make_float4(0.f, 0.f, 0.f, 0.f);
        A0 = f4max(A0, z); A1 = f4max(A1, z);
    }
    ap[0*128] = A0.x; ap[1*128] = A0.y; ap[2*128] = A0.z; ap[3*128] = A0.w;
    ap[4*128] = A1.x; ap[5*128] = A1.y; ap[6*128] = A1.z; ap[7*128] = A1.w;
}

// ---------------- relu + pool4 + bf16 mirror (layer2 acc -> pool2 + mirror slot0)
// thread handles one (g, fi2, b): fo pair (2*fi2, 2*fi2+1)
__global__ __launch_bounds__(256) void k_relu_pool_m(const float* __restrict__ acc,
        float* __restrict__ pool, unsigned* __restrict__ mir) {
    int i = blockIdx.x * 256 + threadIdx.x;   // g*4096 + fi2*128 + b, total 1,048,576
    int g = i >> 12, fi2 = (i >> 7) & 31, b = i & 127;
    const float* ap = acc + (((size_t)g << 2) << 13) + (fi2 << 8) + b;
    float me = 0.f, mo = 0.f;
#pragma unroll
    for (int r = 0; r < 4; ++r) {
        me = fmaxf(me, ap[0]); mo = fmaxf(mo, ap[128]);
        ap += 8192;
    }
    size_t po = ((size_t)g << 13) + (fi2 << 8) + b;
    pool[po] = me; pool[po + 128] = mo;
    mir[i] = packbf(me, mo);
}

// ---------------- FC1 partials: rowsplit 64, 8 b's per thread, 2048 blocks
__global__ __launch_bounds__(256) void k_fc1_part(const float* __restrict__ t3, const float* __restrict__ w,
                           float* __restrict__ part) {
    int blk = blockIdx.x;
    int bg = blk >> 7;
    int rs = (blk >> 1) & 63;
    int j = ((blk & 1) << 8) + threadIdx.x;
    int b0 = bg << 3;
    float a0=0.f,a1=0.f,a2=0.f,a3=0.f,a4=0.f,a5=0.f,a6=0.f,a7=0.f;
    int r0 = rs << 8;
#pragma unroll 4
    for (int row = r0; row < r0 + 256; ++row) {
        float wv = w[((size_t)row << 9) + j];
        const float4* tp = (const float4*)(t3 + ((size_t)row << 7) + b0);
        float4 t0 = tp[0], t1 = tp[1];
        a0 = fmaf(t0.x, wv, a0);
        a1 = fmaf(t0.y, wv, a1);
        a2 = fmaf(t0.z, wv, a2);
        a3 = fmaf(t0.w, wv, a3);
        a4 = fmaf(t1.x, wv, a4);
        a5 = fmaf(t1.y, wv, a5);
        a6 = fmaf(t1.z, wv, a6);
        a7 = fmaf(t1.w, wv, a7);
    }
    float* pp = part + (((size_t)(rs << 7) + b0) << 9) + j;
    pp[0*512]=a0; pp[1*512]=a1; pp[2*512]=a2; pp[3*512]=a3;
    pp[4*512]=a4; pp[5*512]=a5; pp[6*512]=a6; pp[7*512]=a7;
}

__global__ __launch_bounds__(256) void k_fc1_red(const float* __restrict__ part, const float* __restrict__ bias,
                          float* __restrict__ h) {
    int i = blockIdx.x * 256 + threadIdx.x;   // i = b*512 + j
    float a = bias[i & 511];
#pragma unroll 8
    for (int rs = 0; rs < 64; ++rs) a += part[((size_t)rs << 16) + i];
    h[i] = a;
}

// ---------------- batchnorm stats over batch (biased var), store mean | inv_std
__global__ void k_bnstats(const float* __restrict__ h, float* __restrict__ mv) {
    __shared__ float s1[128], s2[128];
    int j = blockIdx.x, t = threadIdx.x;
    float v = h[(size_t)t * 512 + j];
    s1[t] = v; s2[t] = v * v;
    __syncthreads();
    for (int o = 64; o > 0; o >>= 1) {
        if (t < o) { s1[t] += s1[t + o]; s2[t] += s2[t + o]; }
        __syncthreads();
    }
    if (t == 0) {
        float m = s1[0] * (1.f / 128.f);
        float var = s2[0] * (1.f / 128.f) - m * m;
        mv[j] = m;
        mv[512 + j] = rsqrtf(var + 1e-5f);
    }
}

// ---------------- BN apply + relu + FC2 + log_softmax, one block per batch row
__global__ void k_head(const float* __restrict__ h, const float* __restrict__ mv,
                       const float* __restrict__ gamma, const float* __restrict__ beta,
                       const float* __restrict__ w2, const float* __restrict__ b2,
                       float* __restrict__ out) {
    __shared__ float hr[512];
    __shared__ float lg[16];
    int b = blockIdx.x, t = threadIdx.x;   // 64 threads
    for (int j = t; j < 512; j += 64) {
        float x = (h[(size_t)b * 512 + j] - mv[j]) * mv[512 + j] * gamma[j] + beta[j];
        hr[j] = fmaxf(x, 0.f);
    }
    __syncthreads();
    if (t < 10) {
        float a = b2[t];
        for (int j = 0; j < 512; ++j) a += hr[j] * w2[j * 10 + t];
        lg[t] = a;
    }
    __syncthreads();
    if (t == 0) {
        float mx = -1e30f;
        for (int q = 0; q < 10; ++q) mx = fmaxf(mx, lg[q]);
        float sum = 0.f;
        for (int q = 0; q < 10; ++q) sum += expf(lg[q] - mx);
        float ls = logf(sum) + mx;
        for (int q = 0; q < 10; ++q) out[b * 10 + q] = lg[q] - ls;
    }
}

extern "C" void kernel_launch(void* const* d_in, const int* in_sizes, int n_in,
                              void* d_out, int out_size, void* d_ws, size_t ws_size,
                              hipStream_t stream) {
    (void)in_sizes; (void)n_in; (void)out_size;
    const float* x      = (const float*)d_in[0];
    const int*   l0cols = (const int*)d_in[2];
    const float* l0vals = (const float*)d_in[3];
    const int*   l2cols = (const int*)d_in[5];
    const float* l2vals = (const float*)d_in[6];
    const int*   l4cols = (const int*)d_in[8];
    const float* l4vals = (const float*)d_in[9];
    const float* w1   = (const float*)d_in[10];
    const float* b1   = (const float*)d_in[11];
    const float* w2   = (const float*)d_in[12];
    const float* b2   = (const float*)d_in[13];
    const float* w3   = (const float*)d_in[14];
    const float* b3   = (const float*)d_in[15];
    const float* fc1w = (const float*)d_in[16];
    const float* fc1b = (const float*)d_in[17];
    const float* gam  = (const float*)d_in[18];
    const float* bet  = (const float*)d_in[19];
    const float* fc2w = (const float*)d_in[20];
    const float* fc2b = (const float*)d_in[21];
    float* out = (float*)d_out;

    const size_t S1 = 4096 * 128;    // layer-1 basis slot (floats)
    const size_t S2 = 1024 * 4096;   // layer-2 slot (floats); mirror slot = S2/2 dwords
    const size_t S3 = 256 * 8192;    // layer-3 slot (floats); mirror slot = S3/2 dwords

    // fp32 rings shrink to 3 slots (recursion window only); projections read bf16 mirrors.
    // CKP = proj chunk size (mirror ring slots).
    const size_t tailN = 128 * 512 + 1024;
    size_t baseF = 25 * S1 + 3 * S2 + tailN;
    int CKP = (ws_size >= (baseF + 9 * (S2 / 2)) * sizeof(float)) ? 9 : 5;

    float* ws = (float*)d_ws;
    float* basis1 = ws;                                  // 25 slots of S1 (layer-1, fp32)
    float* ring2f = ws + 25 * S1;                        // 3 slots S2; also ring3f (3*S3) + acc3
    unsigned* mir2 = (unsigned*)(ring2f + 3 * S2);       // CKP slots of S2/2 dwords; also mir3
    float* tailp  = (float*)(mir2 + (size_t)CKP * (S2 / 2));
    float* h      = tailp;
    float* mv     = h + 65536;
    float* acc2   = basis1;                              // 8.39M <= 13.1M, basis1 dead
    float* ring3f = ring2f;                              // slot0 = pool2
    float* acc3   = ring2f + 3 * S3;                     // 4*S3 = 2*S2 <= 3*S2
    unsigned* mir3 = mir2;                               // CKP*S3/2 <= CKP*S2/2
    float* part   = basis1;                              // 4.19M, acc2 dead by then

    // ---------------- Layer 1: V=4096, C=128, full fp32 basis ----------------
    k_transpose_x<<<2048, 256, 0, stream>>>(x, basis1);
    for (int k = 1; k < 25; ++k) {
        const float* cur  = basis1 + (size_t)(k - 1) * S1;
        const float* prev = (k >= 2) ? basis1 + (size_t)(k - 2) * S1 : cur;
        float* next = basis1 + (size_t)k * S1;
        k_spmm1<<<1024, 256, 0, stream>>>(l0cols, l0vals, (const float2*)cur,
                                          (const float2*)prev, (float2*)next, k >= 2 ? 1 : 0);
    }
    // pool1 -> ring2f slot0 (fp32, x0 for recursion) + mir2 slot0 (bf16, for proj)
    k_proj1_pool<<<dim3(512, 2), 256, 0, stream>>>(basis1, w1, b1, ring2f, mir2);

    // ---------------- Layer 2: V=1024, C=4096 ----------------
    {
        int cs = 0;
        for (int k = 0; k < 25; ++k) {
            if (k >= 1) {
                const float* cur  = ring2f + (size_t)((k - 1) % 3) * S2;
                const float* prev = ring2f + (size_t)((k >= 2 ? k - 2 : 0) % 3) * S2;
                float* next = ring2f + (size_t)(k % 3) * S2;
                unsigned* mirp = mir2 + (size_t)(k % CKP) * (S2 / 2);
                k_spmm4<10><<<4096, 256, 0, stream>>>(l2cols, l2vals, (const float4*)cur,
                                                      (const float4*)prev, (float4*)next,
                                                      mirp, k >= 2 ? 1 : 0);
            }
            if (k - cs + 1 == CKP || k == 24) {
                k_proj_l2<<<dim3(512, 4), 256, 0, stream>>>(mir2, S2 / 2, w2, acc2, cs, k - cs + 1,
                                                            cs == 0 ? 1 : 0, b2);
                cs = k + 1;
            }
        }
    }
    k_relu_pool_m<<<4096, 256, 0, stream>>>(acc2, ring3f /*pool2 = slot0*/, mir3 /*slot0*/);

    // ---------------- Layer 3: V=256, C=8192 ----------------
    {
        int cs = 0;
        for (int k = 0; k < 25; ++k) {
            if (k >= 1) {
                const float* cur  = ring3f + (size_t)((k - 1) % 3) * S3;
                const float* prev = ring3f + (size_t)((k >= 2 ? k - 2 : 0) % 3) * S3;
                float* next = ring3f + (size_t)(k % 3) * S3;
                unsigned* mirp = mir3 + (size_t)(k % CKP) * (S3 / 2);
                k_spmm4<11><<<2048, 256, 0, stream>>>(l4cols, l4vals, (const float4*)cur,
                                                      (const float4*)prev, (float4*)next,
                                                      mirp, k >= 2 ? 1 : 0);
            }
            if (k - cs + 1 == CKP || k == 24) {
                int kcnt = k - cs + 1;
                k_proj_l3<<<dim3(128, 8), 256, 0, stream>>>(mir3, S3 / 2, w3, acc3, cs, kcnt,
                                                            cs == 0 ? 1 : 0, b3,
                                                            (cs + kcnt == 25) ? 1 : 0);
                cs = k + 1;
            }
        }
    }

    // ---------------- FC1 + BN + FC2 + log_softmax ----------------
    k_fc1_part<<<2048, 256, 0, stream>>>(acc3, fc1w, part);
    k_fc1_red<<<256, 256, 0, stream>>>(part, fc1b, h);
    k_bnstats<<<512, 128, 0, stream>>>(h, mv);
    k_head<<<128, 64, 0, stream>>>(h, mv, gam, bet, fc2w, fc2b, out);
}